// Round 1
// baseline (746.763 us; speedup 1.0000x reference)
//
#include <hip/hip_runtime.h>
#include <hip/hip_bf16.h>

// Problem constants: b=8, c=64, hw=256, RATIO=4, HP=WP=64, N=4096.
#define NB 8
#define NC 64
#define HW 256
#define HP 64
#define NN 4096   // HP*WP

// ---------------------------------------------------------------------------
// K0: transpose up_w [c][o][i][j] -> wT [o][i][c][j]  (65536 floats)
__global__ __launch_bounds__(256) void transw_k(const float* __restrict__ uw,
                                                float* __restrict__ wT) {
    int idx = blockIdx.x * 256 + threadIdx.x;       // 0..65535
    int j = idx & 3;
    int c = (idx >> 2) & 63;
    int i = (idx >> 8) & 3;
    int o = idx >> 10;
    wT[idx] = uw[((c * 64 + o) * 4 + i) * 4 + j];
}

// ---------------------------------------------------------------------------
// K1: maxpool 4x4 stride 4.  x[8,64,256,256] -> xp[8,64,64,64]
__global__ __launch_bounds__(256) void maxpool_k(const float* __restrict__ x,
                                                 float* __restrict__ xp) {
    int idx = blockIdx.x * 256 + threadIdx.x;       // 0..2097151
    int ox = idx & 63;
    int oy = (idx >> 6) & 63;
    int bc = idx >> 12;                              // b*64+c
    const float* p = x + ((long)bc * 256 + oy * 4) * 256 + ox * 4;
    float m = -3.4e38f;
#pragma unroll
    for (int r = 0; r < 4; ++r) {
        float4 v = *(const float4*)(p + r * 256);
        m = fmaxf(m, fmaxf(fmaxf(v.x, v.y), fmaxf(v.z, v.w)));
    }
    xp[idx] = m;
}

// ---------------------------------------------------------------------------
// K2: 3x3 conv (pad 1) + bias + relu.  xp -> xpih [8,64,4096]
// Block: (rowgroup of 4, co-group of 16, b). 256 thr = 16 colgrp x 4 row x 4 coq.
// Input tile in LDS (32 ci per pass, 2 passes), weights via scalar loads.
__global__ __launch_bounds__(256) void conv3x3_k(const float* __restrict__ xp,
                                                 const float* __restrict__ pw,
                                                 const float* __restrict__ pb,
                                                 float* __restrict__ xpih) {
    __shared__ float ins[32 * 6 * 67];              // 51456 B
    int rg = blockIdx.x;                             // 0..15
    int cg = blockIdx.y;                             // 0..3
    int b  = blockIdx.z;                             // 0..7
    int t = threadIdx.x;
    int colg = t & 15;                               // 4-col group
    int r    = (t >> 4) & 3;                         // row within group
    int coq  = t >> 6;                               // 0..3 (wave-uniform)
    int cb = __builtin_amdgcn_readfirstlane(cg * 16 + coq * 4);
    int r0 = rg * 4;
    float acc[4][4];
#pragma unroll
    for (int a = 0; a < 4; ++a)
#pragma unroll
        for (int p = 0; p < 4; ++p) acc[a][p] = 0.f;

    for (int pass = 0; pass < 2; ++pass) {
        int cibase = pass * 32;
        __syncthreads();
        for (int idx = t; idx < 32 * 402; idx += 256) {
            int ci  = idx / 402;
            int rem = idx - ci * 402;
            int ry  = rem / 67;
            int cx  = rem - ry * 67;
            int row = r0 - 1 + ry;
            int col = cx - 1;
            float v = 0.f;
            if (row >= 0 && row < HP && col >= 0 && col < HP && cx < 66)
                v = xp[((b * 64 + cibase + ci) * HP + row) * HP + col];
            ins[idx] = v;
        }
        __syncthreads();
        for (int ci = 0; ci < 32; ++ci) {
            float win[3][6];
#pragma unroll
            for (int dy = 0; dy < 3; ++dy)
#pragma unroll
                for (int dx = 0; dx < 6; ++dx)
                    win[dy][dx] = ins[ci * 402 + (r + dy) * 67 + colg * 4 + dx];
#pragma unroll
            for (int oc = 0; oc < 4; ++oc) {
                const float* wp = pw + ((cb + oc) * 64 + cibase + ci) * 9;  // uniform -> s_load
#pragma unroll
                for (int dy = 0; dy < 3; ++dy)
#pragma unroll
                    for (int dx = 0; dx < 3; ++dx) {
                        float wv = wp[dy * 3 + dx];
#pragma unroll
                        for (int px = 0; px < 4; ++px)
                            acc[oc][px] += win[dy][px + dx] * wv;
                    }
            }
        }
    }
#pragma unroll
    for (int oc = 0; oc < 4; ++oc) {
        int o = cb + oc;
        float bias = pb[o];
        float4 v;
        v.x = fmaxf(acc[oc][0] + bias, 0.f);
        v.y = fmaxf(acc[oc][1] + bias, 0.f);
        v.z = fmaxf(acc[oc][2] + bias, 0.f);
        v.w = fmaxf(acc[oc][3] + bias, 0.f);
        *(float4*)&xpih[((b * 64 + o) * HP + r0 + r) * HP + colg * 4] = v;
    }
}

// ---------------------------------------------------------------------------
// K3: Gram G[b][c][d] += sum_n xpih[c][n]*xpih[d][n]  (n-chunk 128, atomics)
__global__ __launch_bounds__(256) void gram_k(const float* __restrict__ xpih,
                                              float* __restrict__ G) {
    __shared__ float xs[64][132];
    int n0 = blockIdx.x * 128;
    int b  = blockIdx.y;
    int t = threadIdx.x;
#pragma unroll
    for (int l = 0; l < 8; ++l) {
        int f = t + l * 256;                        // float4 index 0..2047
        int row = f >> 5;
        int c4  = (f & 31) * 4;
        float4 v = *(const float4*)&xpih[(b * 64 + row) * NN + n0 + c4];
        *(float4*)&xs[row][c4] = v;
    }
    __syncthreads();
    int td4 = (t & 15) * 4;
    int tc4 = (t >> 4) * 4;
    float acc[4][4];
#pragma unroll
    for (int i = 0; i < 4; ++i)
#pragma unroll
        for (int j = 0; j < 4; ++j) acc[i][j] = 0.f;
#pragma unroll 4
    for (int nn = 0; nn < 128; ++nn) {
        float a0 = xs[tc4 + 0][nn], a1 = xs[tc4 + 1][nn];
        float a2 = xs[tc4 + 2][nn], a3 = xs[tc4 + 3][nn];
        float b0 = xs[td4 + 0][nn], b1 = xs[td4 + 1][nn];
        float b2 = xs[td4 + 2][nn], b3 = xs[td4 + 3][nn];
        acc[0][0] += a0 * b0; acc[0][1] += a0 * b1; acc[0][2] += a0 * b2; acc[0][3] += a0 * b3;
        acc[1][0] += a1 * b0; acc[1][1] += a1 * b1; acc[1][2] += a1 * b2; acc[1][3] += a1 * b3;
        acc[2][0] += a2 * b0; acc[2][1] += a2 * b1; acc[2][2] += a2 * b2; acc[2][3] += a2 * b3;
        acc[3][0] += a3 * b0; acc[3][1] += a3 * b1; acc[3][2] += a3 * b2; acc[3][3] += a3 * b3;
    }
    float* Gb = G + b * 4096;
#pragma unroll
    for (int i = 0; i < 4; ++i)
#pragma unroll
        for (int j = 0; j < 4; ++j)
            atomicAdd(&Gb[(tc4 + i) * 64 + td4 + j], acc[i][j]);
}

// ---------------------------------------------------------------------------
// K4: build L (transposed): LT[b][d][c] = (c==d) - d_c * A_cd * d_d
__global__ void build_L_k(const float* __restrict__ G, float* __restrict__ LT) {
    int b = blockIdx.x;
    int c = threadIdx.x;                             // 64 threads
    __shared__ float nrm[64], dvv[64];
    const float* Gb = G + b * 4096;
    float n = sqrtf(Gb[c * 64 + c]);
    n = fmaxf(n, 1e-12f);
    nrm[c] = n;
    __syncthreads();
    float rs = 0.f;
    for (int d = 0; d < 64; ++d) rs += Gb[c * 64 + d] / (n * nrm[d]);
    float dd = 1.0f / sqrtf(rs + 1e-8f);
    if (!(dd <= 3.0e38f)) dd = 0.0f;                 // replicates isfinite (dd >= 0 or NaN)
    dvv[c] = dd;
    __syncthreads();
    for (int d = 0; d < 64; ++d) {
        float A = Gb[c * 64 + d] / (n * nrm[d]);
        float val = ((c == d) ? 1.0f : 0.0f) - dd * A * dvv[d];
        LT[b * 4096 + d * 64 + c] = val;
    }
}

// ---------------------------------------------------------------------------
// K5: out1[b][c][n] = sum_d L[c][d] * xp[d][n]   (LT is [d][c], scalar loads)
__global__ __launch_bounds__(256) void diffuse_k(const float* __restrict__ LT,
                                                 const float* __restrict__ xp,
                                                 float* __restrict__ out1) {
    int b = blockIdx.y;
    int n = blockIdx.x * 256 + threadIdx.x;
    const float* Lb = LT + b * 4096;
    float acc[64];
#pragma unroll
    for (int c = 0; c < 64; ++c) acc[c] = 0.f;
    for (int d = 0; d < 64; ++d) {
        float v = xp[(b * 64 + d) * NN + n];
        const float* lp = Lb + d * 64;               // uniform -> s_load
#pragma unroll
        for (int c = 0; c < 64; ++c) acc[c] += lp[c] * v;
    }
#pragma unroll
    for (int c = 0; c < 64; ++c) out1[(b * 64 + c) * NN + n] = acc[c];
}

// ---------------------------------------------------------------------------
// K6: C[512][4096] = A[512][4096] @ W[4096][4096], fp32 tiled 64x64, BK=64
__global__ __launch_bounds__(256) void gemm512_k(const float* __restrict__ A,
                                                 const float* __restrict__ W,
                                                 float* __restrict__ C) {
    __shared__ float At[64][68];                     // transposed A tile [k][m]
    __shared__ float Bs[64][68];                     // B tile [k][n]
    int m0 = blockIdx.x * 64;                        // 8 m-tiles
    int n0 = blockIdx.y * 64;                        // 64 n-tiles
    int t  = threadIdx.x;
    int tx = t & 15, ty = t >> 4;
    float acc[4][4];
#pragma unroll
    for (int i = 0; i < 4; ++i)
#pragma unroll
        for (int j = 0; j < 4; ++j) acc[i][j] = 0.f;

    for (int k0 = 0; k0 < 4096; k0 += 64) {
        __syncthreads();
#pragma unroll
        for (int l = 0; l < 4; ++l) {
            int idx = t + l * 256;                   // 0..1023 float4 slots
            int mr = idx >> 4, k4 = (idx & 15) * 4;
            float4 a = *(const float4*)&A[(m0 + mr) * 4096 + k0 + k4];
            At[k4 + 0][mr] = a.x; At[k4 + 1][mr] = a.y;
            At[k4 + 2][mr] = a.z; At[k4 + 3][mr] = a.w;
            int kr = idx >> 4, n4 = (idx & 15) * 4;
            float4 bv = *(const float4*)&W[(k0 + kr) * 4096 + n0 + n4];
            *(float4*)&Bs[kr][n4] = bv;
        }
        __syncthreads();
#pragma unroll 16
        for (int kk = 0; kk < 64; ++kk) {
            float4 a  = *(const float4*)&At[kk][ty * 4];
            float4 bv = *(const float4*)&Bs[kk][tx * 4];
            acc[0][0] += a.x * bv.x; acc[0][1] += a.x * bv.y; acc[0][2] += a.x * bv.z; acc[0][3] += a.x * bv.w;
            acc[1][0] += a.y * bv.x; acc[1][1] += a.y * bv.y; acc[1][2] += a.y * bv.z; acc[1][3] += a.y * bv.w;
            acc[2][0] += a.z * bv.x; acc[2][1] += a.z * bv.y; acc[2][2] += a.z * bv.z; acc[2][3] += a.z * bv.w;
            acc[3][0] += a.w * bv.x; acc[3][1] += a.w * bv.y; acc[3][2] += a.w * bv.z; acc[3][3] += a.w * bv.w;
        }
    }
#pragma unroll
    for (int i = 0; i < 4; ++i) {
        float4 v; v.x = acc[i][0]; v.y = acc[i][1]; v.z = acc[i][2]; v.w = acc[i][3];
        *(float4*)&C[(m0 + ty * 4 + i) * 4096 + n0 + tx * 4] = v;
    }
}

// ---------------------------------------------------------------------------
// K7: convtranspose(k=4,s=4) + bias + identity + relu
// up[b,o,4h+i,4w+j] = sum_c out2[b,c,h,w]*wT[o,i,c,j] + up_b[o]; out = relu(up + x)
__global__ __launch_bounds__(256) void convT_k(const float* __restrict__ out2,
                                               const float* __restrict__ wT,
                                               const float* __restrict__ ub,
                                               const float* __restrict__ x,
                                               float* __restrict__ out) {
    int h = blockIdx.x;                              // 0..63
    int b = blockIdx.y;                              // 0..7
    int w = threadIdx.x & 63;                        // lane = w
    int q = threadIdx.x >> 6;                        // wave -> o-group
    float sv[64];
#pragma unroll
    for (int c = 0; c < 64; ++c)
        sv[c] = out2[((b * 64 + c) * HP + h) * HP + w];
    int ob0 = __builtin_amdgcn_readfirstlane(q * 16);
    for (int oo = 0; oo < 16; ++oo) {
        int o = ob0 + oo;
        float bias = ub[o];
#pragma unroll
        for (int i = 0; i < 4; ++i) {
            const float* wp = wT + ((o * 4 + i) << 8);   // uniform -> s_load
            float ax = 0.f, ay = 0.f, az = 0.f, aw = 0.f;
#pragma unroll
            for (int c = 0; c < 64; ++c) {
                float4 wc = *(const float4*)(wp + c * 4);
                ax += sv[c] * wc.x; ay += sv[c] * wc.y;
                az += sv[c] * wc.z; aw += sv[c] * wc.w;
            }
            int oidx = ((b * 64 + o) * HW + h * 4 + i) * HW + w * 4;
            float4 xi = *(const float4*)&x[oidx];
            float4 r;
            r.x = fmaxf(ax + bias + xi.x, 0.f);
            r.y = fmaxf(ay + bias + xi.y, 0.f);
            r.z = fmaxf(az + bias + xi.z, 0.f);
            r.w = fmaxf(aw + bias + xi.w, 0.f);
            *(float4*)&out[oidx] = r;
        }
    }
}

// ---------------------------------------------------------------------------
extern "C" void kernel_launch(void* const* d_in, const int* in_sizes, int n_in,
                              void* d_out, int out_size, void* d_ws, size_t ws_size,
                              hipStream_t stream) {
    const float* x      = (const float*)d_in[0];
    const float* weight = (const float*)d_in[1];
    const float* pih_w  = (const float*)d_in[2];
    const float* pih_b  = (const float*)d_in[3];
    const float* up_w   = (const float*)d_in[4];
    const float* up_b   = (const float*)d_in[5];
    float* out = (float*)d_out;
    float* ws  = (float*)d_ws;

    // workspace layout (floats)
    float* xp   = ws;                        // 2097152  (8,64,64,64)
    float* xpih = ws + 2097152;              // 2097152  (also reused as out1)
    float* G    = ws + 4194304;              // 32768
    float* LT   = ws + 4227072;              // 32768
    float* wT   = ws + 4259840;              // 65536
    float* out1 = xpih;                      // xpih dead after gram
    float* out2 = xp;                        // xp dead after diffuse

    hipMemsetAsync(G, 0, 32768 * sizeof(float), stream);
    transw_k  <<<256, 256, 0, stream>>>(up_w, wT);
    maxpool_k <<<8192, 256, 0, stream>>>(x, xp);
    conv3x3_k <<<dim3(16, 4, 8), 256, 0, stream>>>(xp, pih_w, pih_b, xpih);
    gram_k    <<<dim3(32, 8), 256, 0, stream>>>(xpih, G);
    build_L_k <<<8, 64, 0, stream>>>(G, LT);
    diffuse_k <<<dim3(16, 8), 256, 0, stream>>>(LT, xp, out1);
    gemm512_k <<<dim3(8, 64), 256, 0, stream>>>(out1, weight, out2);
    convT_k   <<<dim3(64, 8), 256, 0, stream>>>(out2, wT, up_b, x, out);
}

// Round 2
// 466.914 us; speedup vs baseline: 1.5994x; 1.5994x over previous
//
#include <hip/hip_runtime.h>

// Problem constants: b=8, c=64, hw=256, RATIO=4, HP=WP=64, N=4096.
#define NB 8
#define NC 64
#define HW 256
#define HP 64
#define NN 4096   // HP*WP

typedef unsigned short u16;
typedef __attribute__((ext_vector_type(8))) short s16x8;          // MFMA a/b frag (8 bf16)
typedef __attribute__((ext_vector_type(8))) unsigned short u16x8; // 16B bf16 vector
typedef __attribute__((ext_vector_type(4))) float f32x4;          // MFMA acc

__device__ __forceinline__ u16 f2bf(float f) {          // fp32 -> bf16 RNE
    unsigned u = __float_as_uint(f);
    return (u16)((u + 0x7fffu + ((u >> 16) & 1u)) >> 16);
}
__device__ __forceinline__ float bf2f(u16 v) {
    return __uint_as_float(((unsigned)v) << 16);
}

// global -> LDS direct, 16B per lane. LDS dest: wave-uniform base + lane*16.
#define GLOAD16(gsrc, ldst) \
    __builtin_amdgcn_global_load_lds((const __attribute__((address_space(1))) unsigned int*)(gsrc), \
                                     (__attribute__((address_space(3))) unsigned int*)(ldst), 16, 0, 0)

// ---------------------------------------------------------------------------
// K0: transpose up_w [c][o][i][j] -> wTc [o][i][c][j]  (65536 floats)
__global__ __launch_bounds__(256) void transw_k(const float* __restrict__ uw,
                                                float* __restrict__ wT) {
    int idx = blockIdx.x * 256 + threadIdx.x;
    int j = idx & 3;
    int c = (idx >> 2) & 63;
    int i = (idx >> 8) & 3;
    int o = idx >> 10;
    wT[idx] = uw[((c * 64 + o) * 4 + i) * 4 + j];
}

// ---------------------------------------------------------------------------
// K0b: W fp32 [K][N] -> WT bf16 [N][K]  (tiled 64x64 transpose)
__global__ __launch_bounds__(256) void transWb_k(const float* __restrict__ W,
                                                 u16* __restrict__ WTb) {
    __shared__ float tile[64 * 65];
    int k0 = blockIdx.x * 64;
    int n0 = blockIdx.y * 64;
    int t = threadIdx.x;
#pragma unroll
    for (int i = 0; i < 4; ++i) {
        int idx = t + i * 256;                 // float4 id 0..1023
        int r  = idx >> 4;                     // k row
        int c4 = (idx & 15) * 4;               // n col
        float4 v = *(const float4*)&W[(long)(k0 + r) * 4096 + n0 + c4];
        tile[(c4 + 0) * 65 + r] = v.x;
        tile[(c4 + 1) * 65 + r] = v.y;
        tile[(c4 + 2) * 65 + r] = v.z;
        tile[(c4 + 3) * 65 + r] = v.w;
    }
    __syncthreads();
#pragma unroll
    for (int i = 0; i < 2; ++i) {
        int chunk = t + i * 256;               // 0..511
        int nr = chunk >> 3;
        int kc = (chunk & 7) * 8;
        u16x8 o;
#pragma unroll
        for (int j = 0; j < 8; ++j) o[j] = f2bf(tile[nr * 65 + kc + j]);
        *(u16x8*)&WTb[(long)(n0 + nr) * 4096 + k0 + kc] = o;
    }
}

// ---------------------------------------------------------------------------
// K1: maxpool 4x4 stride 4.  x[8,64,256,256] -> xp[8,64,64,64]
__global__ __launch_bounds__(256) void maxpool_k(const float* __restrict__ x,
                                                 float* __restrict__ xp) {
    int idx = blockIdx.x * 256 + threadIdx.x;
    int ox = idx & 63;
    int oy = (idx >> 6) & 63;
    int bc = idx >> 12;
    const float* p = x + ((long)bc * 256 + oy * 4) * 256 + ox * 4;
    float m = -3.4e38f;
#pragma unroll
    for (int r = 0; r < 4; ++r) {
        float4 v = *(const float4*)(p + r * 256);
        m = fmaxf(m, fmaxf(fmaxf(v.x, v.y), fmaxf(v.z, v.w)));
    }
    xp[idx] = m;
}

// ---------------------------------------------------------------------------
// K2: 3x3 conv (pad 1) + bias + relu.  xp -> xpih [8,64,4096]
__global__ __launch_bounds__(256) void conv3x3_k(const float* __restrict__ xp,
                                                 const float* __restrict__ pw,
                                                 const float* __restrict__ pb,
                                                 float* __restrict__ xpih) {
    __shared__ float ins[32 * 6 * 67];
    int rg = blockIdx.x;
    int cg = blockIdx.y;
    int b  = blockIdx.z;
    int t = threadIdx.x;
    int colg = t & 15;
    int r    = (t >> 4) & 3;
    int coq  = t >> 6;
    int cb = __builtin_amdgcn_readfirstlane(cg * 16 + coq * 4);
    int r0 = rg * 4;
    float acc[4][4];
#pragma unroll
    for (int a = 0; a < 4; ++a)
#pragma unroll
        for (int p = 0; p < 4; ++p) acc[a][p] = 0.f;

    for (int pass = 0; pass < 2; ++pass) {
        int cibase = pass * 32;
        __syncthreads();
        for (int idx = t; idx < 32 * 402; idx += 256) {
            int ci  = idx / 402;
            int rem = idx - ci * 402;
            int ry  = rem / 67;
            int cx  = rem - ry * 67;
            int row = r0 - 1 + ry;
            int col = cx - 1;
            float v = 0.f;
            if (row >= 0 && row < HP && col >= 0 && col < HP && cx < 66)
                v = xp[((b * 64 + cibase + ci) * HP + row) * HP + col];
            ins[idx] = v;
        }
        __syncthreads();
        for (int ci = 0; ci < 32; ++ci) {
            float win[3][6];
#pragma unroll
            for (int dy = 0; dy < 3; ++dy)
#pragma unroll
                for (int dx = 0; dx < 6; ++dx)
                    win[dy][dx] = ins[ci * 402 + (r + dy) * 67 + colg * 4 + dx];
#pragma unroll
            for (int oc = 0; oc < 4; ++oc) {
                const float* wp = pw + ((cb + oc) * 64 + cibase + ci) * 9;
#pragma unroll
                for (int dy = 0; dy < 3; ++dy)
#pragma unroll
                    for (int dx = 0; dx < 3; ++dx) {
                        float wv = wp[dy * 3 + dx];
#pragma unroll
                        for (int px = 0; px < 4; ++px)
                            acc[oc][px] += win[dy][px + dx] * wv;
                    }
            }
        }
    }
#pragma unroll
    for (int oc = 0; oc < 4; ++oc) {
        int o = cb + oc;
        float bias = pb[o];
        float4 v;
        v.x = fmaxf(acc[oc][0] + bias, 0.f);
        v.y = fmaxf(acc[oc][1] + bias, 0.f);
        v.z = fmaxf(acc[oc][2] + bias, 0.f);
        v.w = fmaxf(acc[oc][3] + bias, 0.f);
        *(float4*)&xpih[((b * 64 + o) * HP + r0 + r) * HP + colg * 4] = v;
    }
}

// ---------------------------------------------------------------------------
// K3: Gram G[b][c][d] += sum_n xpih[c][n]*xpih[d][n]
__global__ __launch_bounds__(256) void gram_k(const float* __restrict__ xpih,
                                              float* __restrict__ G) {
    __shared__ float xs[64][132];
    int n0 = blockIdx.x * 128;
    int b  = blockIdx.y;
    int t = threadIdx.x;
#pragma unroll
    for (int l = 0; l < 8; ++l) {
        int f = t + l * 256;
        int row = f >> 5;
        int c4  = (f & 31) * 4;
        float4 v = *(const float4*)&xpih[(b * 64 + row) * NN + n0 + c4];
        *(float4*)&xs[row][c4] = v;
    }
    __syncthreads();
    int td4 = (t & 15) * 4;
    int tc4 = (t >> 4) * 4;
    float acc[4][4];
#pragma unroll
    for (int i = 0; i < 4; ++i)
#pragma unroll
        for (int j = 0; j < 4; ++j) acc[i][j] = 0.f;
#pragma unroll 4
    for (int nn = 0; nn < 128; ++nn) {
        float a0 = xs[tc4 + 0][nn], a1 = xs[tc4 + 1][nn];
        float a2 = xs[tc4 + 2][nn], a3 = xs[tc4 + 3][nn];
        float b0 = xs[td4 + 0][nn], b1 = xs[td4 + 1][nn];
        float b2 = xs[td4 + 2][nn], b3 = xs[td4 + 3][nn];
        acc[0][0] += a0 * b0; acc[0][1] += a0 * b1; acc[0][2] += a0 * b2; acc[0][3] += a0 * b3;
        acc[1][0] += a1 * b0; acc[1][1] += a1 * b1; acc[1][2] += a1 * b2; acc[1][3] += a1 * b3;
        acc[2][0] += a2 * b0; acc[2][1] += a2 * b1; acc[2][2] += a2 * b2; acc[2][3] += a2 * b3;
        acc[3][0] += a3 * b0; acc[3][1] += a3 * b1; acc[3][2] += a3 * b2; acc[3][3] += a3 * b3;
    }
    float* Gb = G + b * 4096;
#pragma unroll
    for (int i = 0; i < 4; ++i)
#pragma unroll
        for (int j = 0; j < 4; ++j)
            atomicAdd(&Gb[(tc4 + i) * 64 + td4 + j], acc[i][j]);
}

// ---------------------------------------------------------------------------
// K4: build L (transposed): LT[b][d][c] = (c==d) - d_c * A_cd * d_d
__global__ void build_L_k(const float* __restrict__ G, float* __restrict__ LT) {
    int b = blockIdx.x;
    int c = threadIdx.x;
    __shared__ float nrm[64], dvv[64];
    const float* Gb = G + b * 4096;
    float n = sqrtf(Gb[c * 64 + c]);
    n = fmaxf(n, 1e-12f);
    nrm[c] = n;
    __syncthreads();
    float rs = 0.f;
    for (int d = 0; d < 64; ++d) rs += Gb[c * 64 + d] / (n * nrm[d]);
    float dd = 1.0f / sqrtf(rs + 1e-8f);
    if (!(dd <= 3.0e38f)) dd = 0.0f;
    dvv[c] = dd;
    __syncthreads();
    for (int d = 0; d < 64; ++d) {
        float A = Gb[c * 64 + d] / (n * nrm[d]);
        float val = ((c == d) ? 1.0f : 0.0f) - dd * A * dvv[d];
        LT[b * 4096 + d * 64 + c] = val;
    }
}

// ---------------------------------------------------------------------------
// K5: out1[b][c][n] = sum_d L[c][d] * xp[d][n]  -> bf16 (GEMM A operand)
__global__ __launch_bounds__(256) void diffuse_k(const float* __restrict__ LT,
                                                 const float* __restrict__ xp,
                                                 u16* __restrict__ out1) {
    int b = blockIdx.y;
    int n = blockIdx.x * 256 + threadIdx.x;
    const float* Lb = LT + b * 4096;
    float acc[64];
#pragma unroll
    for (int c = 0; c < 64; ++c) acc[c] = 0.f;
    for (int d = 0; d < 64; ++d) {
        float v = xp[(b * 64 + d) * NN + n];
        const float* lp = Lb + d * 64;
#pragma unroll
        for (int c = 0; c < 64; ++c) acc[c] += lp[c] * v;
    }
#pragma unroll
    for (int c = 0; c < 64; ++c) out1[(b * 64 + c) * NN + n] = f2bf(acc[c]);
}

// ---------------------------------------------------------------------------
// K6: bf16 MFMA GEMM.  Cp[z][512][4096](bf16) += A[512][4096](bf16) @ WT^T
// A row-major [M][K] bf16; WT row-major [N][K] bf16. 128x128 tile, BK=64,
// 4 waves x (64x64), K-split 4 (z = K-slice of 1024). XOR-swizzled LDS.
#define KSPLIT 4
#define KSLICE 1024
__global__ __launch_bounds__(256) void gemm_mfma_k(const u16* __restrict__ A,
                                                   const u16* __restrict__ WT,
                                                   u16* __restrict__ Cp) {
    __shared__ alignas(16) u16 ldsA[8192];   // 128 rows x 64 k (128B/row)
    __shared__ alignas(16) u16 ldsB[8192];
    int bid = blockIdx.x;                    // 512 blocks
    int swz = (bid & 7) * 64 + (bid >> 3);   // XCD-chunked (512 % 8 == 0)
    int m0 = (swz & 3) * 128;
    int n0 = ((swz >> 2) & 31) * 128;
    int z  = swz >> 7;
    int t = threadIdx.x;
    int w = t >> 6, l = t & 63;
    int wr = w >> 1, wc = w & 1;
    int lr = l & 15;                         // fragment row/col lane
    int lk = (l >> 4) << 4;                  // k-byte subgroup {0,16,32,48}

    f32x4 acc[4][4];
#pragma unroll
    for (int mf = 0; mf < 4; ++mf)
#pragma unroll
        for (int nf = 0; nf < 4; ++nf) acc[mf][nf] = (f32x4){0.f, 0.f, 0.f, 0.f};

    const char* Ab = (const char*)(A  + (long)m0 * 4096 + z * KSLICE);
    const char* Bb = (const char*)(WT + (long)n0 * 4096 + z * KSLICE);

    for (int k0 = 0; k0 < KSLICE; k0 += 64) {
        __syncthreads();
#pragma unroll
        for (int i = 0; i < 4; ++i) {
            int d   = i * 4096 + t * 16;     // linear LDS byte dest
            int row = d >> 7;
            int off = d & 127;
            int sk  = off ^ ((row & 7) << 4);   // pre-swizzled global source
            GLOAD16(Ab + (long)row * 8192 + k0 * 2 + sk, (char*)ldsA + d);
            GLOAD16(Bb + (long)row * 8192 + k0 * 2 + sk, (char*)ldsB + d);
        }
        __syncthreads();
#pragma unroll
        for (int kk = 0; kk < 2; ++kk) {
            s16x8 af[4], bf[4];
#pragma unroll
            for (int f = 0; f < 4; ++f) {
                int ar = wr * 64 + f * 16 + lr;
                af[f] = *(const s16x8*)((const char*)ldsA + ar * 128 +
                                        ((kk * 64 + lk) ^ ((ar & 7) << 4)));
                int br = wc * 64 + f * 16 + lr;
                bf[f] = *(const s16x8*)((const char*)ldsB + br * 128 +
                                        ((kk * 64 + lk) ^ ((br & 7) << 4)));
            }
#pragma unroll
            for (int mf = 0; mf < 4; ++mf)
#pragma unroll
                for (int nf = 0; nf < 4; ++nf)
                    acc[mf][nf] = __builtin_amdgcn_mfma_f32_16x16x32_bf16(
                        af[mf], bf[nf], acc[mf][nf], 0, 0, 0);
        }
    }
    // epilogue: C/D layout col=lane&15, row=(lane>>4)*4+reg  [m89-verified]
    u16* Cz = Cp + (long)z * 2097152;
#pragma unroll
    for (int mf = 0; mf < 4; ++mf)
#pragma unroll
        for (int nf = 0; nf < 4; ++nf)
#pragma unroll
            for (int r = 0; r < 4; ++r) {
                int row = m0 + wr * 64 + mf * 16 + (l >> 4) * 4 + r;
                int col = n0 + wc * 64 + nf * 16 + lr;
                Cz[(long)row * 4096 + col] = f2bf(acc[mf][nf][r]);
            }
}

// ---------------------------------------------------------------------------
// K6b: out2 fp32 = sum_z Cp[z] (bf16 partials)
__global__ __launch_bounds__(256) void reduce4_k(const u16* __restrict__ Cp,
                                                 float* __restrict__ out2) {
    long i = (long)(blockIdx.x * 256 + threadIdx.x) * 8;
    float s[8] = {0.f, 0.f, 0.f, 0.f, 0.f, 0.f, 0.f, 0.f};
#pragma unroll
    for (int zz = 0; zz < KSPLIT; ++zz) {
        u16x8 v = *(const u16x8*)&Cp[(long)zz * 2097152 + i];
#pragma unroll
        for (int j = 0; j < 8; ++j) s[j] += bf2f(v[j]);
    }
    float4 o0 = make_float4(s[0], s[1], s[2], s[3]);
    float4 o1 = make_float4(s[4], s[5], s[6], s[7]);
    *(float4*)&out2[i]     = o0;
    *(float4*)&out2[i + 4] = o1;
}

// ---------------------------------------------------------------------------
// K7: convtranspose(k=4,s=4) + bias + identity + relu
__global__ __launch_bounds__(256) void convT_k(const float* __restrict__ out2,
                                               const float* __restrict__ wT,
                                               const float* __restrict__ ub,
                                               const float* __restrict__ x,
                                               float* __restrict__ out) {
    int h = blockIdx.x;
    int b = blockIdx.y;
    int w = threadIdx.x & 63;
    int q = threadIdx.x >> 6;
    float sv[64];
#pragma unroll
    for (int c = 0; c < 64; ++c)
        sv[c] = out2[((b * 64 + c) * HP + h) * HP + w];
    int ob0 = __builtin_amdgcn_readfirstlane(q * 16);
    for (int oo = 0; oo < 16; ++oo) {
        int o = ob0 + oo;
        float bias = ub[o];
#pragma unroll
        for (int i = 0; i < 4; ++i) {
            const float* wp = wT + ((o * 4 + i) << 8);
            float ax = 0.f, ay = 0.f, az = 0.f, aw = 0.f;
#pragma unroll
            for (int c = 0; c < 64; ++c) {
                float4 wc = *(const float4*)(wp + c * 4);
                ax += sv[c] * wc.x; ay += sv[c] * wc.y;
                az += sv[c] * wc.z; aw += sv[c] * wc.w;
            }
            int oidx = ((b * 64 + o) * HW + h * 4 + i) * HW + w * 4;
            float4 xi = *(const float4*)&x[oidx];
            float4 rr;
            rr.x = fmaxf(ax + bias + xi.x, 0.f);
            rr.y = fmaxf(ay + bias + xi.y, 0.f);
            rr.z = fmaxf(az + bias + xi.z, 0.f);
            rr.w = fmaxf(aw + bias + xi.w, 0.f);
            *(float4*)&out[oidx] = rr;
        }
    }
}

// ---------------------------------------------------------------------------
extern "C" void kernel_launch(void* const* d_in, const int* in_sizes, int n_in,
                              void* d_out, int out_size, void* d_ws, size_t ws_size,
                              hipStream_t stream) {
    const float* x      = (const float*)d_in[0];
    const float* weight = (const float*)d_in[1];
    const float* pih_w  = (const float*)d_in[2];
    const float* pih_b  = (const float*)d_in[3];
    const float* up_w   = (const float*)d_in[4];
    const float* up_b   = (const float*)d_in[5];
    float* out = (float*)d_out;
    float* ws  = (float*)d_ws;

    // workspace layout (float offsets)
    float* xp    = ws;                         // 2,097,152 f  (8,64,64,64)
    float* xpih  = ws + 2097152;               // 2,097,152 f  fp32 conv out
    float* G     = ws + 4194304;               // 32,768 f
    float* LT    = ws + 4227072;               // 32,768 f
    float* wTc   = ws + 4259840;               // 65,536 f (convT weights)
    u16*   WTb   = (u16*)(ws + 4325376);       // 8,388,608 f region: WT bf16 [4096][4096]
    u16*   Cp    = (u16*)(ws + 12713984);      // 4,194,304 f region: 4 bf16 partials
    u16*   Ab16  = (u16*)xpih;                 // A bf16 reuses xpih (dead after gram)
    float* out1f = xpih;                       // (unused name retained)
    float* out2  = xp;                         // xp dead after diffuse
    (void)out1f;

    hipMemsetAsync(G, 0, 32768 * sizeof(float), stream);
    transw_k   <<<256, 256, 0, stream>>>(up_w, wTc);
    transWb_k  <<<dim3(64, 64), 256, 0, stream>>>(weight, WTb);
    maxpool_k  <<<8192, 256, 0, stream>>>(x, xp);
    conv3x3_k  <<<dim3(16, 4, 8), 256, 0, stream>>>(xp, pih_w, pih_b, xpih);
    gram_k     <<<dim3(32, 8), 256, 0, stream>>>(xpih, G);
    build_L_k  <<<8, 64, 0, stream>>>(G, LT);
    diffuse_k  <<<dim3(16, 8), 256, 0, stream>>>(LT, xp, Ab16);
    gemm_mfma_k<<<512, 256, 0, stream>>>(Ab16, WTb, Cp);
    reduce4_k  <<<1024, 256, 0, stream>>>(Cp, out2);
    convT_k    <<<dim3(64, 8), 256, 0, stream>>>(out2, wTc, up_b, x, out);
}

// Round 3
// 279.988 us; speedup vs baseline: 2.6671x; 1.6676x over previous
//
#include <hip/hip_runtime.h>

// Problem constants: b=8, c=64, hw=256, RATIO=4, HP=WP=64, N=4096.
#define NB 8
#define NC 64
#define HW 256
#define HP 64
#define NN 4096   // HP*WP

typedef unsigned short u16;
typedef __attribute__((ext_vector_type(8))) short s16x8;          // MFMA a/b frag (8 bf16)
typedef __attribute__((ext_vector_type(8))) unsigned short u16x8; // 16B bf16 vector
typedef __attribute__((ext_vector_type(4))) float f32x4;          // MFMA acc

__device__ __forceinline__ u16 f2bf(float f) {          // fp32 -> bf16 RNE
    unsigned u = __float_as_uint(f);
    return (u16)((u + 0x7fffu + ((u >> 16) & 1u)) >> 16);
}
__device__ __forceinline__ float bf2f(u16 v) {
    return __uint_as_float(((unsigned)v) << 16);
}

// global -> LDS direct, 16B per lane. LDS dest: wave-uniform base + lane*16.
#define GLOAD16(gsrc, ldst) \
    __builtin_amdgcn_global_load_lds((const __attribute__((address_space(1))) unsigned int*)(gsrc), \
                                     (__attribute__((address_space(3))) unsigned int*)(ldst), 16, 0, 0)

// ---------------------------------------------------------------------------
// K0: up_w [c][o][i][j] fp32 -> Wb bf16 [n=(o*4+i)*4+j][c]  (convT B^T operand)
__global__ __launch_bounds__(256) void transwb_k(const float* __restrict__ uw,
                                                 u16* __restrict__ Wb) {
    int idx = blockIdx.x * 256 + threadIdx.x;   // 0..65535
    int c = idx & 63;
    int n = idx >> 6;                           // (o,i,j)
    int o = n >> 4, i = (n >> 2) & 3, j = n & 3;
    Wb[idx] = f2bf(uw[((c * 64 + o) * 4 + i) * 4 + j]);
}

// ---------------------------------------------------------------------------
// K0b: W fp32 [K][N] -> WT bf16 [N][K]  (tiled 64x64 transpose)
__global__ __launch_bounds__(256) void transWb_k(const float* __restrict__ W,
                                                 u16* __restrict__ WTb) {
    __shared__ float tile[64 * 65];
    int k0 = blockIdx.x * 64;
    int n0 = blockIdx.y * 64;
    int t = threadIdx.x;
#pragma unroll
    for (int i = 0; i < 4; ++i) {
        int idx = t + i * 256;                 // float4 id 0..1023
        int r  = idx >> 4;                     // k row
        int c4 = (idx & 15) * 4;               // n col
        float4 v = *(const float4*)&W[(long)(k0 + r) * 4096 + n0 + c4];
        tile[(c4 + 0) * 65 + r] = v.x;
        tile[(c4 + 1) * 65 + r] = v.y;
        tile[(c4 + 2) * 65 + r] = v.z;
        tile[(c4 + 3) * 65 + r] = v.w;
    }
    __syncthreads();
#pragma unroll
    for (int i = 0; i < 2; ++i) {
        int chunk = t + i * 256;               // 0..511
        int nr = chunk >> 3;
        int kc = (chunk & 7) * 8;
        u16x8 o;
#pragma unroll
        for (int j = 0; j < 8; ++j) o[j] = f2bf(tile[nr * 65 + kc + j]);
        *(u16x8*)&WTb[(long)(n0 + nr) * 4096 + k0 + kc] = o;
    }
}

// ---------------------------------------------------------------------------
// K1: maxpool 4x4 stride 4.  x[8,64,256,256] -> xp[8,64,64,64]
__global__ __launch_bounds__(256) void maxpool_k(const float* __restrict__ x,
                                                 float* __restrict__ xp) {
    int idx = blockIdx.x * 256 + threadIdx.x;
    int ox = idx & 63;
    int oy = (idx >> 6) & 63;
    int bc = idx >> 12;
    const float* p = x + ((long)bc * 256 + oy * 4) * 256 + ox * 4;
    float m = -3.4e38f;
#pragma unroll
    for (int r = 0; r < 4; ++r) {
        float4 v = *(const float4*)(p + r * 256);
        m = fmaxf(m, fmaxf(fmaxf(v.x, v.y), fmaxf(v.z, v.w)));
    }
    xp[idx] = m;
}

// ---------------------------------------------------------------------------
// K2: 3x3 conv (pad 1) + bias + relu.  xp -> xpih [8,64,4096]
__global__ __launch_bounds__(256) void conv3x3_k(const float* __restrict__ xp,
                                                 const float* __restrict__ pw,
                                                 const float* __restrict__ pb,
                                                 float* __restrict__ xpih) {
    __shared__ float ins[32 * 6 * 67];
    int rg = blockIdx.x;
    int cg = blockIdx.y;
    int b  = blockIdx.z;
    int t = threadIdx.x;
    int colg = t & 15;
    int r    = (t >> 4) & 3;
    int coq  = t >> 6;
    int cb = __builtin_amdgcn_readfirstlane(cg * 16 + coq * 4);
    int r0 = rg * 4;
    float acc[4][4];
#pragma unroll
    for (int a = 0; a < 4; ++a)
#pragma unroll
        for (int p = 0; p < 4; ++p) acc[a][p] = 0.f;

    for (int pass = 0; pass < 2; ++pass) {
        int cibase = pass * 32;
        __syncthreads();
        for (int idx = t; idx < 32 * 402; idx += 256) {
            int ci  = idx / 402;
            int rem = idx - ci * 402;
            int ry  = rem / 67;
            int cx  = rem - ry * 67;
            int row = r0 - 1 + ry;
            int col = cx - 1;
            float v = 0.f;
            if (row >= 0 && row < HP && col >= 0 && col < HP && cx < 66)
                v = xp[((b * 64 + cibase + ci) * HP + row) * HP + col];
            ins[idx] = v;
        }
        __syncthreads();
        for (int ci = 0; ci < 32; ++ci) {
            float win[3][6];
#pragma unroll
            for (int dy = 0; dy < 3; ++dy)
#pragma unroll
                for (int dx = 0; dx < 6; ++dx)
                    win[dy][dx] = ins[ci * 402 + (r + dy) * 67 + colg * 4 + dx];
#pragma unroll
            for (int oc = 0; oc < 4; ++oc) {
                const float* wp = pw + ((cb + oc) * 64 + cibase + ci) * 9;
#pragma unroll
                for (int dy = 0; dy < 3; ++dy)
#pragma unroll
                    for (int dx = 0; dx < 3; ++dx) {
                        float wv = wp[dy * 3 + dx];
#pragma unroll
                        for (int px = 0; px < 4; ++px)
                            acc[oc][px] += win[dy][px + dx] * wv;
                    }
            }
        }
    }
#pragma unroll
    for (int oc = 0; oc < 4; ++oc) {
        int o = cb + oc;
        float bias = pb[o];
        float4 v;
        v.x = fmaxf(acc[oc][0] + bias, 0.f);
        v.y = fmaxf(acc[oc][1] + bias, 0.f);
        v.z = fmaxf(acc[oc][2] + bias, 0.f);
        v.w = fmaxf(acc[oc][3] + bias, 0.f);
        *(float4*)&xpih[((b * 64 + o) * HP + r0 + r) * HP + colg * 4] = v;
    }
}

// ---------------------------------------------------------------------------
// K3: Gram G[b][c][d] += sum_n xpih[c][n]*xpih[d][n]
__global__ __launch_bounds__(256) void gram_k(const float* __restrict__ xpih,
                                              float* __restrict__ G) {
    __shared__ float xs[64][132];
    int n0 = blockIdx.x * 128;
    int b  = blockIdx.y;
    int t = threadIdx.x;
#pragma unroll
    for (int l = 0; l < 8; ++l) {
        int f = t + l * 256;
        int row = f >> 5;
        int c4  = (f & 31) * 4;
        float4 v = *(const float4*)&xpih[(b * 64 + row) * NN + n0 + c4];
        *(float4*)&xs[row][c4] = v;
    }
    __syncthreads();
    int td4 = (t & 15) * 4;
    int tc4 = (t >> 4) * 4;
    float acc[4][4];
#pragma unroll
    for (int i = 0; i < 4; ++i)
#pragma unroll
        for (int j = 0; j < 4; ++j) acc[i][j] = 0.f;
#pragma unroll 4
    for (int nn = 0; nn < 128; ++nn) {
        float a0 = xs[tc4 + 0][nn], a1 = xs[tc4 + 1][nn];
        float a2 = xs[tc4 + 2][nn], a3 = xs[tc4 + 3][nn];
        float b0 = xs[td4 + 0][nn], b1 = xs[td4 + 1][nn];
        float b2 = xs[td4 + 2][nn], b3 = xs[td4 + 3][nn];
        acc[0][0] += a0 * b0; acc[0][1] += a0 * b1; acc[0][2] += a0 * b2; acc[0][3] += a0 * b3;
        acc[1][0] += a1 * b0; acc[1][1] += a1 * b1; acc[1][2] += a1 * b2; acc[1][3] += a1 * b3;
        acc[2][0] += a2 * b0; acc[2][1] += a2 * b1; acc[2][2] += a2 * b2; acc[2][3] += a2 * b3;
        acc[3][0] += a3 * b0; acc[3][1] += a3 * b1; acc[3][2] += a3 * b2; acc[3][3] += a3 * b3;
    }
    float* Gb = G + b * 4096;
#pragma unroll
    for (int i = 0; i < 4; ++i)
#pragma unroll
        for (int j = 0; j < 4; ++j)
            atomicAdd(&Gb[(tc4 + i) * 64 + td4 + j], acc[i][j]);
}

// ---------------------------------------------------------------------------
// K4: build L (transposed): LT[b][d][c] = (c==d) - d_c * A_cd * d_d
__global__ void build_L_k(const float* __restrict__ G, float* __restrict__ LT) {
    int b = blockIdx.x;
    int c = threadIdx.x;
    __shared__ float nrm[64], dvv[64];
    const float* Gb = G + b * 4096;
    float n = sqrtf(Gb[c * 64 + c]);
    n = fmaxf(n, 1e-12f);
    nrm[c] = n;
    __syncthreads();
    float rs = 0.f;
    for (int d = 0; d < 64; ++d) rs += Gb[c * 64 + d] / (n * nrm[d]);
    float dd = 1.0f / sqrtf(rs + 1e-8f);
    if (!(dd <= 3.0e38f)) dd = 0.0f;
    dvv[c] = dd;
    __syncthreads();
    for (int d = 0; d < 64; ++d) {
        float A = Gb[c * 64 + d] / (n * nrm[d]);
        float val = ((c == d) ? 1.0f : 0.0f) - dd * A * dvv[d];
        LT[b * 4096 + d * 64 + c] = val;
    }
}

// ---------------------------------------------------------------------------
// K5: out1[b][c][n] = sum_d L[c][d] * xp[d][n]  -> bf16 (GEMM A operand)
__global__ __launch_bounds__(256) void diffuse_k(const float* __restrict__ LT,
                                                 const float* __restrict__ xp,
                                                 u16* __restrict__ out1) {
    int b = blockIdx.y;
    int n = blockIdx.x * 256 + threadIdx.x;
    const float* Lb = LT + b * 4096;
    float acc[64];
#pragma unroll
    for (int c = 0; c < 64; ++c) acc[c] = 0.f;
    for (int d = 0; d < 64; ++d) {
        float v = xp[(b * 64 + d) * NN + n];
        const float* lp = Lb + d * 64;
#pragma unroll
        for (int c = 0; c < 64; ++c) acc[c] += lp[c] * v;
    }
#pragma unroll
    for (int c = 0; c < 64; ++c) out1[(b * 64 + c) * NN + n] = f2bf(acc[c]);
}

// ---------------------------------------------------------------------------
// K6: bf16 MFMA GEMM.  Cp[z][512][4096](bf16) += A[512][4096](bf16) @ WT^T
// 128x128 tile, BK=64, 4 waves x (64x64), K-split 4. XOR-swizzled LDS.
#define KSPLIT 4
#define KSLICE 1024
__global__ __launch_bounds__(256) void gemm_mfma_k(const u16* __restrict__ A,
                                                   const u16* __restrict__ WT,
                                                   u16* __restrict__ Cp) {
    __shared__ alignas(16) u16 ldsA[8192];   // 128 rows x 64 k (128B/row)
    __shared__ alignas(16) u16 ldsB[8192];
    int bid = blockIdx.x;                    // 512 blocks
    int swz = (bid & 7) * 64 + (bid >> 3);   // XCD-chunked (512 % 8 == 0)
    int m0 = (swz & 3) * 128;
    int n0 = ((swz >> 2) & 31) * 128;
    int z  = swz >> 7;
    int t = threadIdx.x;
    int w = t >> 6, l = t & 63;
    int wr = w >> 1, wc = w & 1;
    int lr = l & 15;                         // fragment row/col lane
    int lk = (l >> 4) << 4;                  // k-byte subgroup {0,16,32,48}

    f32x4 acc[4][4];
#pragma unroll
    for (int mf = 0; mf < 4; ++mf)
#pragma unroll
        for (int nf = 0; nf < 4; ++nf) acc[mf][nf] = (f32x4){0.f, 0.f, 0.f, 0.f};

    const char* Ab = (const char*)(A  + (long)m0 * 4096 + z * KSLICE);
    const char* Bb = (const char*)(WT + (long)n0 * 4096 + z * KSLICE);

    for (int k0 = 0; k0 < KSLICE; k0 += 64) {
        __syncthreads();
#pragma unroll
        for (int i = 0; i < 4; ++i) {
            int d   = i * 4096 + t * 16;     // linear LDS byte dest
            int row = d >> 7;
            int off = d & 127;
            int sk  = off ^ ((row & 7) << 4);   // pre-swizzled global source
            GLOAD16(Ab + (long)row * 8192 + k0 * 2 + sk, (char*)ldsA + d);
            GLOAD16(Bb + (long)row * 8192 + k0 * 2 + sk, (char*)ldsB + d);
        }
        __syncthreads();
#pragma unroll
        for (int kk = 0; kk < 2; ++kk) {
            s16x8 af[4], bf[4];
#pragma unroll
            for (int f = 0; f < 4; ++f) {
                int ar = wr * 64 + f * 16 + lr;
                af[f] = *(const s16x8*)((const char*)ldsA + ar * 128 +
                                        ((kk * 64 + lk) ^ ((ar & 7) << 4)));
                int br = wc * 64 + f * 16 + lr;
                bf[f] = *(const s16x8*)((const char*)ldsB + br * 128 +
                                        ((kk * 64 + lk) ^ ((br & 7) << 4)));
            }
#pragma unroll
            for (int mf = 0; mf < 4; ++mf)
#pragma unroll
                for (int nf = 0; nf < 4; ++nf)
                    acc[mf][nf] = __builtin_amdgcn_mfma_f32_16x16x32_bf16(
                        af[mf], bf[nf], acc[mf][nf], 0, 0, 0);
        }
    }
    // epilogue: C/D layout col=lane&15, row=(lane>>4)*4+reg
    u16* Cz = Cp + (long)z * 2097152;
#pragma unroll
    for (int mf = 0; mf < 4; ++mf)
#pragma unroll
        for (int nf = 0; nf < 4; ++nf)
#pragma unroll
            for (int r = 0; r < 4; ++r) {
                int row = m0 + wr * 64 + mf * 16 + (l >> 4) * 4 + r;
                int col = n0 + wc * 64 + nf * 16 + lr;
                Cz[(long)row * 4096 + col] = f2bf(acc[mf][nf][r]);
            }
}

// ---------------------------------------------------------------------------
// K6b: A2[b*4096+n][c] (bf16) = sum_z Cp[z][b*64+c][n]   (reduce + transpose)
__global__ __launch_bounds__(256) void reduce4T_k(const u16* __restrict__ Cp,
                                                  u16* __restrict__ A2) {
    __shared__ float xs[64 * 65];
    int n0 = blockIdx.x * 64;
    int b  = blockIdx.y;
    int t = threadIdx.x;
    int c = t >> 2, seg = t & 3;
    float s[16];
#pragma unroll
    for (int k = 0; k < 16; ++k) s[k] = 0.f;
#pragma unroll
    for (int z = 0; z < KSPLIT; ++z) {
        const u16* p = Cp + ((long)z * 512 + b * 64 + c) * 4096 + n0 + seg * 16;
        u16x8 v0 = *(const u16x8*)p;
        u16x8 v1 = *(const u16x8*)(p + 8);
#pragma unroll
        for (int k = 0; k < 8; ++k) {
            s[k]     += bf2f(v0[k]);
            s[8 + k] += bf2f(v1[k]);
        }
    }
#pragma unroll
    for (int k = 0; k < 16; ++k) xs[c * 65 + seg * 16 + k] = s[k];
    __syncthreads();
    int n = t >> 2, q = t & 3;
    u16x8 o0, o1;
#pragma unroll
    for (int k = 0; k < 8; ++k) o0[k] = f2bf(xs[(q * 16 + k) * 65 + n]);
#pragma unroll
    for (int k = 0; k < 8; ++k) o1[k] = f2bf(xs[(q * 16 + 8 + k) * 65 + n]);
    u16* dst = A2 + ((long)b * 4096 + n0 + n) * 64 + q * 16;
    *(u16x8*)dst = o0;
    *(u16x8*)(dst + 8) = o1;
}

// ---------------------------------------------------------------------------
// K7: convT as MFMA GEMM.  C[m=32768(b,h,w)][n=1024(o,i,j)] = A2 @ Wb^T, K=64.
// Epilogue: out[b,o,4h+i,4w+j] = relu(C + up_b[o] + x[same]).
// 128x128 tile, 4 waves x (64x64), single K shot, XOR-swizzled LDS.
__global__ __launch_bounds__(256) void convT_mfma_k(const u16* __restrict__ A2,
                                                    const u16* __restrict__ Wb,
                                                    const float* __restrict__ ub,
                                                    const float* __restrict__ x,
                                                    float* __restrict__ out) {
    __shared__ alignas(16) u16 ldsA[128 * 64];   // 16 KB
    __shared__ alignas(16) u16 ldsB[128 * 64];   // 16 KB
    int mt = blockIdx.x;                         // 0..255
    int nt = blockIdx.y;                         // 0..7
    int m0 = mt * 128;
    int n0 = nt * 128;
    int t = threadIdx.x;
    int w = t >> 6, l = t & 63;
    int wr = w >> 1, wc = w & 1;
    int lr = l & 15;
    int lkb = (l >> 4) << 4;                     // k-byte subgroup {0,16,32,48}

    // stage A tile (contiguous 16KB) and B tile (contiguous 16KB), swizzled src
    const char* Ab = (const char*)(A2 + (long)m0 * 64);
    const char* Bb = (const char*)(Wb + (long)n0 * 64);
#pragma unroll
    for (int i = 0; i < 4; ++i) {
        int d = i * 4096 + t * 16;
        int srcoff = (d & ~127) | ((d & 127) ^ (((d >> 7) & 7) << 4));
        GLOAD16(Ab + srcoff, (char*)ldsA + d);
        GLOAD16(Bb + srcoff, (char*)ldsB + d);
    }
    __syncthreads();

    f32x4 acc[4][4];
#pragma unroll
    for (int mf = 0; mf < 4; ++mf)
#pragma unroll
        for (int nf = 0; nf < 4; ++nf) acc[mf][nf] = (f32x4){0.f, 0.f, 0.f, 0.f};

#pragma unroll
    for (int kk = 0; kk < 2; ++kk) {
        s16x8 af[4], bfg[4];
#pragma unroll
        for (int f = 0; f < 4; ++f) {
            int ar = wr * 64 + f * 16 + lr;
            af[f] = *(const s16x8*)((const char*)ldsA + ar * 128 +
                                    ((kk * 64 + lkb) ^ ((ar & 7) << 4)));
            int br = wc * 64 + f * 16 + lr;
            bfg[f] = *(const s16x8*)((const char*)ldsB + br * 128 +
                                     ((kk * 64 + lkb) ^ ((br & 7) << 4)));
        }
#pragma unroll
        for (int mf = 0; mf < 4; ++mf)
#pragma unroll
            for (int nf = 0; nf < 4; ++nf)
                acc[mf][nf] = __builtin_amdgcn_mfma_f32_16x16x32_bf16(
                    af[mf], bfg[nf], acc[mf][nf], 0, 0, 0);
    }

    // epilogue: C/D col=lane&15 -> (i,j); row -> pixel m
    int rowb = (l >> 4) * 4;
    int i4 = lr >> 2, j4 = lr & 3;               // (i,j) from lane
#pragma unroll
    for (int nf = 0; nf < 4; ++nf) {
        int ncol = n0 + wc * 64 + nf * 16;       // multiple of 16 -> o uniform
        int o = ncol >> 4;
        float bias = ub[o];
#pragma unroll
        for (int mf = 0; mf < 4; ++mf) {
#pragma unroll
            for (int r = 0; r < 4; ++r) {
                int m = m0 + wr * 64 + mf * 16 + rowb + r;
                int b = m >> 12;
                int pix = m & 4095;
                int h = pix >> 6, ww = pix & 63;
                int addr = ((b * 64 + o) * 256 + h * 4 + i4) * 256 + ww * 4 + j4;
                float v = acc[mf][nf][r] + bias + x[addr];
                out[addr] = fmaxf(v, 0.f);
            }
        }
    }
}

// ---------------------------------------------------------------------------
extern "C" void kernel_launch(void* const* d_in, const int* in_sizes, int n_in,
                              void* d_out, int out_size, void* d_ws, size_t ws_size,
                              hipStream_t stream) {
    const float* x      = (const float*)d_in[0];
    const float* weight = (const float*)d_in[1];
    const float* pih_w  = (const float*)d_in[2];
    const float* pih_b  = (const float*)d_in[3];
    const float* up_w   = (const float*)d_in[4];
    const float* up_b   = (const float*)d_in[5];
    float* out = (float*)d_out;
    float* ws  = (float*)d_ws;

    // workspace layout (float offsets)
    float* xp    = ws;                         // 2,097,152 f  (8,64,64,64)
    float* xpih  = ws + 2097152;               // 2,097,152 f  fp32 conv out
    float* G     = ws + 4194304;               // 32,768 f
    float* LT    = ws + 4227072;               // 32,768 f
    u16*   Wb    = (u16*)(ws + 4259840);       // 65,536 u16 (convT B^T bf16)
    u16*   WTb   = (u16*)(ws + 4325376);       // 16,777,216 u16: WT bf16 [4096][4096]
    u16*   Cp    = (u16*)(ws + 12713984);      // 8,388,608 u16: 4 bf16 partials
    u16*   Ab16  = (u16*)xpih;                 // A bf16 reuses xpih (dead after gram)
    u16*   A2    = (u16*)xp;                   // out2T bf16 reuses xp (dead after diffuse)

    hipMemsetAsync(G, 0, 32768 * sizeof(float), stream);
    transwb_k   <<<256, 256, 0, stream>>>(up_w, Wb);
    transWb_k   <<<dim3(64, 64), 256, 0, stream>>>(weight, WTb);
    maxpool_k   <<<8192, 256, 0, stream>>>(x, xp);
    conv3x3_k   <<<dim3(16, 4, 8), 256, 0, stream>>>(xp, pih_w, pih_b, xpih);
    gram_k      <<<dim3(32, 8), 256, 0, stream>>>(xpih, G);
    build_L_k   <<<8, 64, 0, stream>>>(G, LT);
    diffuse_k   <<<dim3(16, 8), 256, 0, stream>>>(LT, xp, Ab16);
    gemm_mfma_k <<<512, 256, 0, stream>>>(Ab16, WTb, Cp);
    reduce4T_k  <<<dim3(64, 8), 256, 0, stream>>>(Cp, A2);
    convT_mfma_k<<<dim3(256, 8), 256, 0, stream>>>(A2, Wb, up_b, x, out);
}

// Round 4
// 220.926 us; speedup vs baseline: 3.3801x; 1.2673x over previous
//
#include <hip/hip_runtime.h>

// Problem constants: b=8, c=64, hw=256, RATIO=4, HP=WP=64, N=4096.
#define NB 8
#define NC 64
#define HW 256
#define HP 64
#define NN 4096   // HP*WP

typedef unsigned short u16;
typedef __attribute__((ext_vector_type(8))) short s16x8;          // MFMA a/b frag (8 bf16)
typedef __attribute__((ext_vector_type(8))) unsigned short u16x8; // 16B bf16 vector
typedef __attribute__((ext_vector_type(4))) float f32x4;          // MFMA acc

__device__ __forceinline__ u16 f2bf(float f) {          // fp32 -> bf16 RNE
    unsigned u = __float_as_uint(f);
    return (u16)((u + 0x7fffu + ((u >> 16) & 1u)) >> 16);
}
__device__ __forceinline__ float bf2f(u16 v) {
    return __uint_as_float(((unsigned)v) << 16);
}

// global -> LDS direct, 16B per lane. LDS dest: wave-uniform base + lane*16.
#define GLOAD16(gsrc, ldst) \
    __builtin_amdgcn_global_load_lds((const __attribute__((address_space(1))) unsigned int*)(gsrc), \
                                     (__attribute__((address_space(3))) unsigned int*)(ldst), 16, 0, 0)

// ---------------------------------------------------------------------------
// K0: up_w [c][o][i][j] fp32 -> Wb bf16 [n=(o*4+i)*4+j][c]  (convT B^T operand)
__global__ __launch_bounds__(256) void transwb_k(const float* __restrict__ uw,
                                                 u16* __restrict__ Wb) {
    int idx = blockIdx.x * 256 + threadIdx.x;   // 0..65535
    int c = idx & 63;
    int n = idx >> 6;                           // (o,i,j)
    int o = n >> 4, i = (n >> 2) & 3, j = n & 3;
    Wb[idx] = f2bf(uw[((c * 64 + o) * 4 + i) * 4 + j]);
}

// ---------------------------------------------------------------------------
// K0b: W fp32 [K][N] -> WT bf16 [N][K]  (tiled 64x64 transpose)
__global__ __launch_bounds__(256) void transWb_k(const float* __restrict__ W,
                                                 u16* __restrict__ WTb) {
    __shared__ float tile[64 * 65];
    int k0 = blockIdx.x * 64;
    int n0 = blockIdx.y * 64;
    int t = threadIdx.x;
#pragma unroll
    for (int i = 0; i < 4; ++i) {
        int idx = t + i * 256;                 // float4 id 0..1023
        int r  = idx >> 4;                     // k row
        int c4 = (idx & 15) * 4;               // n col
        float4 v = *(const float4*)&W[(long)(k0 + r) * 4096 + n0 + c4];
        tile[(c4 + 0) * 65 + r] = v.x;
        tile[(c4 + 1) * 65 + r] = v.y;
        tile[(c4 + 2) * 65 + r] = v.z;
        tile[(c4 + 3) * 65 + r] = v.w;
    }
    __syncthreads();
#pragma unroll
    for (int i = 0; i < 2; ++i) {
        int chunk = t + i * 256;               // 0..511
        int nr = chunk >> 3;
        int kc = (chunk & 7) * 8;
        u16x8 o;
#pragma unroll
        for (int j = 0; j < 8; ++j) o[j] = f2bf(tile[nr * 65 + kc + j]);
        *(u16x8*)&WTb[(long)(n0 + nr) * 4096 + k0 + kc] = o;
    }
}

// ---------------------------------------------------------------------------
// K0c: pack pih_w [o][ci][3][3] -> Bpack bf16 MFMA fragment order.
// Bpack[((s*4 + nf)*64 + lane)*8 + e] = w[o=nf*16+(lane&15)][ci=ch*32+(lane>>4)*8+e][dy][dx]
// where s = (dy*3+dx)*2 + ch.
__global__ __launch_bounds__(256) void bpack_k(const float* __restrict__ pw,
                                               u16* __restrict__ Bpack) {
    int idx = blockIdx.x * 256 + threadIdx.x;   // 0..36863
    if (idx >= 36864) return;
    int e = idx & 7, l = (idx >> 3) & 63, nf = (idx >> 9) & 3, s = idx >> 11;
    int ch = s & 1, kd = s >> 1;
    int dy = kd / 3, dx = kd % 3;
    int o  = nf * 16 + (l & 15);
    int ci = ch * 32 + (l >> 4) * 8 + e;
    Bpack[idx] = f2bf(pw[((o * 64 + ci) * 3 + dy) * 3 + dx]);
}

// ---------------------------------------------------------------------------
// K1: maxpool 4x4 stride 4.  x[8,64,256,256] -> xp[8,64,64,64]
__global__ __launch_bounds__(256) void maxpool_k(const float* __restrict__ x,
                                                 float* __restrict__ xp) {
    int idx = blockIdx.x * 256 + threadIdx.x;
    int ox = idx & 63;
    int oy = (idx >> 6) & 63;
    int bc = idx >> 12;
    const float* p = x + ((long)bc * 256 + oy * 4) * 256 + ox * 4;
    float m = -3.4e38f;
#pragma unroll
    for (int r = 0; r < 4; ++r) {
        float4 v = *(const float4*)(p + r * 256);
        m = fmaxf(m, fmaxf(fmaxf(v.x, v.y), fmaxf(v.z, v.w)));
    }
    xp[idx] = m;
}

// ---------------------------------------------------------------------------
// K1b: xp NCHW fp32 -> xpc NHWC bf16 (per (b,y) row; LDS-tiled transpose)
__global__ __launch_bounds__(256) void nhwc_k(const float* __restrict__ xp,
                                              u16* __restrict__ xpc) {
    __shared__ float tile[64 * 65];
    int bid = blockIdx.x;                       // 512: b = bid>>6, y = bid&63
    int b = bid >> 6, y = bid & 63;
    int t = threadIdx.x;
#pragma unroll
    for (int i = 0; i < 4; ++i) {
        int fid = i * 256 + t;                  // 0..1023
        int c = fid >> 4, x4 = (fid & 15) * 4;
        float4 v = *(const float4*)&xp[(((long)(b * 64 + c) * 64) + y) * 64 + x4];
        tile[c * 65 + x4 + 0] = v.x;
        tile[c * 65 + x4 + 1] = v.y;
        tile[c * 65 + x4 + 2] = v.z;
        tile[c * 65 + x4 + 3] = v.w;
    }
    __syncthreads();
#pragma unroll
    for (int j = 0; j < 2; ++j) {
        int o = j * 256 + t;                    // 0..511
        int x = o >> 3, c8 = o & 7;
        u16x8 ov;
#pragma unroll
        for (int e = 0; e < 8; ++e) ov[e] = f2bf(tile[(c8 * 8 + e) * 65 + x]);
        *(u16x8*)&xpc[((long)(b * 64 + y) * 64 + x) * 64 + c8 * 8] = ov;
    }
}

// ---------------------------------------------------------------------------
// K2: conv3x3 as implicit-GEMM MFMA.  M=row of 64 px, N=64 oc, K=576.
// Block = (b,y). LDS: 3 input rows x 66 x-slots (halo zeroed) x 64 ci bf16,
// XOR-swizzled (coff ^= (xslot&7)<<4) on both staging-source and read.
__global__ __launch_bounds__(256) void conv_mfma_k(const u16* __restrict__ xpc,
                                                   const u16* __restrict__ Bpack,
                                                   const float* __restrict__ pb,
                                                   float* __restrict__ xpih) {
    __shared__ alignas(16) u16 ldsIn[3 * 66 * 64];   // 25344 B
    int bid = blockIdx.x;
    int b = bid >> 6, y = bid & 63;
    int t = threadIdx.x;
    int w = t >> 6, l = t & 63;
    int lr = l & 15, ksub = l >> 4;

    // halo zero fill: slots 0 and 65 of each of the 3 rows
    if (t < 48) {
        int r = t >> 4, q = t & 15;
        int off = r * 8448 + (q < 8 ? q * 16 : 8320 + (q - 8) * 16);
        *(u16x8*)((char*)ldsIn + off) = (u16x8){0, 0, 0, 0, 0, 0, 0, 0};
    }
    // stage input rows y-1..y+1 (8KB each), pre-swizzled global source
#pragma unroll
    for (int i = 0; i < 6; ++i) {
        int r  = i >> 1;
        int ya = y - 1 + r;
        int wro = (i & 1) * 4096 + t * 16;      // within-row byte 0..8191
        int dst = r * 8448 + 128 + wro;
        if (ya >= 0 && ya < 64) {
            int xsl = 1 + (wro >> 7);
            int srcoff = (wro & ~127) | ((wro & 127) ^ ((xsl & 7) << 4));
            GLOAD16((const char*)xpc + (long)(b * 64 + ya) * 8192 + srcoff,
                    (char*)ldsIn + dst);
        } else {
            *(u16x8*)((char*)ldsIn + dst) = (u16x8){0, 0, 0, 0, 0, 0, 0, 0};
        }
    }
    __syncthreads();

    f32x4 acc[4];
#pragma unroll
    for (int mf = 0; mf < 4; ++mf) acc[mf] = (f32x4){0.f, 0.f, 0.f, 0.f};

#pragma unroll
    for (int kd = 0; kd < 9; ++kd) {
        int dy = kd / 3, dx = kd % 3;
#pragma unroll
        for (int ch = 0; ch < 2; ++ch) {
            int s = kd * 2 + ch;
            s16x8 bfrag = *(const s16x8*)(Bpack + ((s * 4 + w) * 64 + l) * 8);
#pragma unroll
            for (int mf = 0; mf < 4; ++mf) {
                int xsl  = mf * 16 + lr + dx;
                int coff = (ch * 64 + ksub * 16) ^ ((xsl & 7) << 4);
                s16x8 af = *(const s16x8*)((const char*)ldsIn +
                                           dy * 8448 + xsl * 128 + coff);
                acc[mf] = __builtin_amdgcn_mfma_f32_16x16x32_bf16(
                    af, bfrag, acc[mf], 0, 0, 0);
            }
        }
    }
    // epilogue: o = w*16+lr (n), x = mf*16 + ksub*4 + r (m); NCHW fp32
    int o = w * 16 + lr;
    float bias = pb[o];
    float* dst = xpih + ((long)(b * 64 + o) * 64 + y) * 64;
#pragma unroll
    for (int mf = 0; mf < 4; ++mf)
#pragma unroll
        for (int r = 0; r < 4; ++r) {
            int x = mf * 16 + ksub * 4 + r;
            dst[x] = fmaxf(acc[mf][r] + bias, 0.f);
        }
}

// ---------------------------------------------------------------------------
// K3: Gram G[b][c][d] += sum_n xpih[c][n]*xpih[d][n]
__global__ __launch_bounds__(256) void gram_k(const float* __restrict__ xpih,
                                              float* __restrict__ G) {
    __shared__ float xs[64][132];
    int n0 = blockIdx.x * 128;
    int b  = blockIdx.y;
    int t = threadIdx.x;
#pragma unroll
    for (int l = 0; l < 8; ++l) {
        int f = t + l * 256;
        int row = f >> 5;
        int c4  = (f & 31) * 4;
        float4 v = *(const float4*)&xpih[(b * 64 + row) * NN + n0 + c4];
        *(float4*)&xs[row][c4] = v;
    }
    __syncthreads();
    int td4 = (t & 15) * 4;
    int tc4 = (t >> 4) * 4;
    float acc[4][4];
#pragma unroll
    for (int i = 0; i < 4; ++i)
#pragma unroll
        for (int j = 0; j < 4; ++j) acc[i][j] = 0.f;
#pragma unroll 4
    for (int nn = 0; nn < 128; ++nn) {
        float a0 = xs[tc4 + 0][nn], a1 = xs[tc4 + 1][nn];
        float a2 = xs[tc4 + 2][nn], a3 = xs[tc4 + 3][nn];
        float b0 = xs[td4 + 0][nn], b1 = xs[td4 + 1][nn];
        float b2 = xs[td4 + 2][nn], b3 = xs[td4 + 3][nn];
        acc[0][0] += a0 * b0; acc[0][1] += a0 * b1; acc[0][2] += a0 * b2; acc[0][3] += a0 * b3;
        acc[1][0] += a1 * b0; acc[1][1] += a1 * b1; acc[1][2] += a1 * b2; acc[1][3] += a1 * b3;
        acc[2][0] += a2 * b0; acc[2][1] += a2 * b1; acc[2][2] += a2 * b2; acc[2][3] += a2 * b3;
        acc[3][0] += a3 * b0; acc[3][1] += a3 * b1; acc[3][2] += a3 * b2; acc[3][3] += a3 * b3;
    }
    float* Gb = G + b * 4096;
#pragma unroll
    for (int i = 0; i < 4; ++i)
#pragma unroll
        for (int j = 0; j < 4; ++j)
            atomicAdd(&Gb[(tc4 + i) * 64 + td4 + j], acc[i][j]);
}

// ---------------------------------------------------------------------------
// K4: build L (transposed): LT[b][d][c] = (c==d) - d_c * A_cd * d_d
__global__ void build_L_k(const float* __restrict__ G, float* __restrict__ LT) {
    int b = blockIdx.x;
    int c = threadIdx.x;
    __shared__ float nrm[64], dvv[64];
    const float* Gb = G + b * 4096;
    float n = sqrtf(Gb[c * 64 + c]);
    n = fmaxf(n, 1e-12f);
    nrm[c] = n;
    __syncthreads();
    float rs = 0.f;
    for (int d = 0; d < 64; ++d) rs += Gb[c * 64 + d] / (n * nrm[d]);
    float dd = 1.0f / sqrtf(rs + 1e-8f);
    if (!(dd <= 3.0e38f)) dd = 0.0f;
    dvv[c] = dd;
    __syncthreads();
    for (int d = 0; d < 64; ++d) {
        float A = Gb[c * 64 + d] / (n * nrm[d]);
        float val = ((c == d) ? 1.0f : 0.0f) - dd * A * dvv[d];
        LT[b * 4096 + d * 64 + c] = val;
    }
}

// ---------------------------------------------------------------------------
// K5: out1[b][c][n] = sum_d L[c][d] * xp[d][n]  -> bf16 (GEMM A operand)
__global__ __launch_bounds__(256) void diffuse_k(const float* __restrict__ LT,
                                                 const float* __restrict__ xp,
                                                 u16* __restrict__ out1) {
    int b = blockIdx.y;
    int n = blockIdx.x * 256 + threadIdx.x;
    const float* Lb = LT + b * 4096;
    float acc[64];
#pragma unroll
    for (int c = 0; c < 64; ++c) acc[c] = 0.f;
    for (int d = 0; d < 64; ++d) {
        float v = xp[(b * 64 + d) * NN + n];
        const float* lp = Lb + d * 64;
#pragma unroll
        for (int c = 0; c < 64; ++c) acc[c] += lp[c] * v;
    }
#pragma unroll
    for (int c = 0; c < 64; ++c) out1[(b * 64 + c) * NN + n] = f2bf(acc[c]);
}

// ---------------------------------------------------------------------------
// K6: bf16 MFMA GEMM.  Cp[z][512][4096](bf16) += A[512][4096](bf16) @ WT^T
// 128x128 tile, BK=64, 4 waves x (64x64), K-split 4. XOR-swizzled LDS.
#define KSPLIT 4
#define KSLICE 1024
__global__ __launch_bounds__(256) void gemm_mfma_k(const u16* __restrict__ A,
                                                   const u16* __restrict__ WT,
                                                   u16* __restrict__ Cp) {
    __shared__ alignas(16) u16 ldsA[8192];   // 128 rows x 64 k (128B/row)
    __shared__ alignas(16) u16 ldsB[8192];
    int bid = blockIdx.x;                    // 512 blocks
    int swz = (bid & 7) * 64 + (bid >> 3);   // XCD-chunked (512 % 8 == 0)
    int m0 = (swz & 3) * 128;
    int n0 = ((swz >> 2) & 31) * 128;
    int z  = swz >> 7;
    int t = threadIdx.x;
    int w = t >> 6, l = t & 63;
    int wr = w >> 1, wc = w & 1;
    int lr = l & 15;                         // fragment row/col lane
    int lk = (l >> 4) << 4;                  // k-byte subgroup {0,16,32,48}

    f32x4 acc[4][4];
#pragma unroll
    for (int mf = 0; mf < 4; ++mf)
#pragma unroll
        for (int nf = 0; nf < 4; ++nf) acc[mf][nf] = (f32x4){0.f, 0.f, 0.f, 0.f};

    const char* Ab = (const char*)(A  + (long)m0 * 4096 + z * KSLICE);
    const char* Bb = (const char*)(WT + (long)n0 * 4096 + z * KSLICE);

    for (int k0 = 0; k0 < KSLICE; k0 += 64) {
        __syncthreads();
#pragma unroll
        for (int i = 0; i < 4; ++i) {
            int d   = i * 4096 + t * 16;     // linear LDS byte dest
            int row = d >> 7;
            int off = d & 127;
            int sk  = off ^ ((row & 7) << 4);   // pre-swizzled global source
            GLOAD16(Ab + (long)row * 8192 + k0 * 2 + sk, (char*)ldsA + d);
            GLOAD16(Bb + (long)row * 8192 + k0 * 2 + sk, (char*)ldsB + d);
        }
        __syncthreads();
#pragma unroll
        for (int kk = 0; kk < 2; ++kk) {
            s16x8 af[4], bf[4];
#pragma unroll
            for (int f = 0; f < 4; ++f) {
                int ar = wr * 64 + f * 16 + lr;
                af[f] = *(const s16x8*)((const char*)ldsA + ar * 128 +
                                        ((kk * 64 + lk) ^ ((ar & 7) << 4)));
                int br = wc * 64 + f * 16 + lr;
                bf[f] = *(const s16x8*)((const char*)ldsB + br * 128 +
                                        ((kk * 64 + lk) ^ ((br & 7) << 4)));
            }
#pragma unroll
            for (int mf = 0; mf < 4; ++mf)
#pragma unroll
                for (int nf = 0; nf < 4; ++nf)
                    acc[mf][nf] = __builtin_amdgcn_mfma_f32_16x16x32_bf16(
                        af[mf], bf[nf], acc[mf][nf], 0, 0, 0);
        }
    }
    // epilogue: C/D layout col=lane&15, row=(lane>>4)*4+reg
    u16* Cz = Cp + (long)z * 2097152;
#pragma unroll
    for (int mf = 0; mf < 4; ++mf)
#pragma unroll
        for (int nf = 0; nf < 4; ++nf)
#pragma unroll
            for (int r = 0; r < 4; ++r) {
                int row = m0 + wr * 64 + mf * 16 + (l >> 4) * 4 + r;
                int col = n0 + wc * 64 + nf * 16 + lr;
                Cz[(long)row * 4096 + col] = f2bf(acc[mf][nf][r]);
            }
}

// ---------------------------------------------------------------------------
// K6b: A2[b*4096+n][c] (bf16) = sum_z Cp[z][b*64+c][n]   (reduce + transpose)
__global__ __launch_bounds__(256) void reduce4T_k(const u16* __restrict__ Cp,
                                                  u16* __restrict__ A2) {
    __shared__ float xs[64 * 65];
    int n0 = blockIdx.x * 64;
    int b  = blockIdx.y;
    int t = threadIdx.x;
    int c = t >> 2, seg = t & 3;
    float s[16];
#pragma unroll
    for (int k = 0; k < 16; ++k) s[k] = 0.f;
#pragma unroll
    for (int z = 0; z < KSPLIT; ++z) {
        const u16* p = Cp + ((long)z * 512 + b * 64 + c) * 4096 + n0 + seg * 16;
        u16x8 v0 = *(const u16x8*)p;
        u16x8 v1 = *(const u16x8*)(p + 8);
#pragma unroll
        for (int k = 0; k < 8; ++k) {
            s[k]     += bf2f(v0[k]);
            s[8 + k] += bf2f(v1[k]);
        }
    }
#pragma unroll
    for (int k = 0; k < 16; ++k) xs[c * 65 + seg * 16 + k] = s[k];
    __syncthreads();
    int n = t >> 2, q = t & 3;
    u16x8 o0, o1;
#pragma unroll
    for (int k = 0; k < 8; ++k) o0[k] = f2bf(xs[(q * 16 + k) * 65 + n]);
#pragma unroll
    for (int k = 0; k < 8; ++k) o1[k] = f2bf(xs[(q * 16 + 8 + k) * 65 + n]);
    u16* dst = A2 + ((long)b * 4096 + n0 + n) * 64 + q * 16;
    *(u16x8*)dst = o0;
    *(u16x8*)(dst + 8) = o1;
}

// ---------------------------------------------------------------------------
// K7: convT as MFMA GEMM.  C[m=32768(b,h,w)][n=1024(o,i,j)] = A2 @ Wb^T, K=64.
// Epilogue: out[b,o,4h+i,4w+j] = relu(C + up_b[o] + x[same]).
__global__ __launch_bounds__(256) void convT_mfma_k(const u16* __restrict__ A2,
                                                    const u16* __restrict__ Wb,
                                                    const float* __restrict__ ub,
                                                    const float* __restrict__ x,
                                                    float* __restrict__ out) {
    __shared__ alignas(16) u16 ldsA[128 * 64];   // 16 KB
    __shared__ alignas(16) u16 ldsB[128 * 64];   // 16 KB
    int mt = blockIdx.x;                         // 0..255
    int nt = blockIdx.y;                         // 0..7
    int m0 = mt * 128;
    int n0 = nt * 128;
    int t = threadIdx.x;
    int w = t >> 6, l = t & 63;
    int wr = w >> 1, wc = w & 1;
    int lr = l & 15;
    int lkb = (l >> 4) << 4;                     // k-byte subgroup {0,16,32,48}

    const char* Ab = (const char*)(A2 + (long)m0 * 64);
    const char* Bb = (const char*)(Wb + (long)n0 * 64);
#pragma unroll
    for (int i = 0; i < 4; ++i) {
        int d = i * 4096 + t * 16;
        int srcoff = (d & ~127) | ((d & 127) ^ (((d >> 7) & 7) << 4));
        GLOAD16(Ab + srcoff, (char*)ldsA + d);
        GLOAD16(Bb + srcoff, (char*)ldsB + d);
    }
    __syncthreads();

    f32x4 acc[4][4];
#pragma unroll
    for (int mf = 0; mf < 4; ++mf)
#pragma unroll
        for (int nf = 0; nf < 4; ++nf) acc[mf][nf] = (f32x4){0.f, 0.f, 0.f, 0.f};

#pragma unroll
    for (int kk = 0; kk < 2; ++kk) {
        s16x8 af[4], bfg[4];
#pragma unroll
        for (int f = 0; f < 4; ++f) {
            int ar = wr * 64 + f * 16 + lr;
            af[f] = *(const s16x8*)((const char*)ldsA + ar * 128 +
                                    ((kk * 64 + lkb) ^ ((ar & 7) << 4)));
            int br = wc * 64 + f * 16 + lr;
            bfg[f] = *(const s16x8*)((const char*)ldsB + br * 128 +
                                     ((kk * 64 + lkb) ^ ((br & 7) << 4)));
        }
#pragma unroll
        for (int mf = 0; mf < 4; ++mf)
#pragma unroll
            for (int nf = 0; nf < 4; ++nf)
                acc[mf][nf] = __builtin_amdgcn_mfma_f32_16x16x32_bf16(
                    af[mf], bfg[nf], acc[mf][nf], 0, 0, 0);
    }

    int rowb = (l >> 4) * 4;
    int i4 = lr >> 2, j4 = lr & 3;               // (i,j) from lane
#pragma unroll
    for (int nf = 0; nf < 4; ++nf) {
        int ncol = n0 + wc * 64 + nf * 16;       // multiple of 16 -> o uniform
        int o = ncol >> 4;
        float bias = ub[o];
#pragma unroll
        for (int mf = 0; mf < 4; ++mf) {
#pragma unroll
            for (int r = 0; r < 4; ++r) {
                int m = m0 + wr * 64 + mf * 16 + rowb + r;
                int b = m >> 12;
                int pix = m & 4095;
                int h = pix >> 6, ww = pix & 63;
                int addr = ((b * 64 + o) * 256 + h * 4 + i4) * 256 + ww * 4 + j4;
                float v = acc[mf][nf][r] + bias + x[addr];
                out[addr] = fmaxf(v, 0.f);
            }
        }
    }
}

// ---------------------------------------------------------------------------
extern "C" void kernel_launch(void* const* d_in, const int* in_sizes, int n_in,
                              void* d_out, int out_size, void* d_ws, size_t ws_size,
                              hipStream_t stream) {
    const float* x      = (const float*)d_in[0];
    const float* weight = (const float*)d_in[1];
    const float* pih_w  = (const float*)d_in[2];
    const float* pih_b  = (const float*)d_in[3];
    const float* up_w   = (const float*)d_in[4];
    const float* up_b   = (const float*)d_in[5];
    float* out = (float*)d_out;
    float* ws  = (float*)d_ws;

    // workspace layout (float offsets)
    float* xp    = ws;                         // 2,097,152 f  (8,64,64,64)
    float* xpih  = ws + 2097152;               // 2,097,152 f  fp32 conv out
    float* G     = ws + 4194304;               // 32,768 f
    float* LT    = ws + 4227072;               // 32,768 f
    u16*   Wb    = (u16*)(ws + 4259840);       // 65,536 u16 (convT B^T bf16)
    u16*   WTb   = (u16*)(ws + 4325376);       // 16,777,216 u16: WT bf16 [4096][4096]
    u16*   Cp    = (u16*)(ws + 12713984);      // 8,388,608 u16: 4 bf16 partials
    u16*   Ab16  = (u16*)xpih;                 // A bf16 reuses xpih (dead after gram)
    u16*   A2    = (u16*)xp;                   // out2T bf16 reuses xp (dead after diffuse)
    // conv scratch aliases Cp region (dead until gemm_mfma_k writes it):
    u16*   xpc   = Cp;                         // 2,097,152 u16 NHWC bf16
    u16*   Bpack = Cp + 2097152;               // 36,864 u16 packed conv weights

    hipMemsetAsync(G, 0, 32768 * sizeof(float), stream);
    transwb_k   <<<256, 256, 0, stream>>>(up_w, Wb);
    transWb_k   <<<dim3(64, 64), 256, 0, stream>>>(weight, WTb);
    bpack_k     <<<144, 256, 0, stream>>>(pih_w, Bpack);
    maxpool_k   <<<8192, 256, 0, stream>>>(x, xp);
    nhwc_k      <<<512, 256, 0, stream>>>(xp, xpc);
    conv_mfma_k <<<512, 256, 0, stream>>>(xpc, Bpack, pih_b, xpih);
    gram_k      <<<dim3(32, 8), 256, 0, stream>>>(xpih, G);
    build_L_k   <<<8, 64, 0, stream>>>(G, LT);
    diffuse_k   <<<dim3(16, 8), 256, 0, stream>>>(LT, xp, Ab16);
    gemm_mfma_k <<<512, 256, 0, stream>>>(Ab16, WTb, Cp);
    reduce4T_k  <<<dim3(64, 8), 256, 0, stream>>>(Cp, A2);
    convT_mfma_k<<<dim3(256, 8), 256, 0, stream>>>(A2, Wb, up_b, x, out);
}

// Round 5
// 200.551 us; speedup vs baseline: 3.7236x; 1.1016x over previous
//
#include <hip/hip_runtime.h>

// Problem constants: b=8, c=64, hw=256, RATIO=4, HP=WP=64, N=4096.
#define NB 8
#define NC 64
#define HW 256
#define HP 64
#define NN 4096   // HP*WP

typedef unsigned short u16;
typedef __attribute__((ext_vector_type(8))) short s16x8;          // MFMA a/b frag (8 bf16)
typedef __attribute__((ext_vector_type(8))) unsigned short u16x8; // 16B bf16 vector
typedef __attribute__((ext_vector_type(4))) float f32x4;          // MFMA acc

__device__ __forceinline__ u16 f2bf(float f) {          // fp32 -> bf16 RNE
    unsigned u = __float_as_uint(f);
    return (u16)((u + 0x7fffu + ((u >> 16) & 1u)) >> 16);
}
__device__ __forceinline__ float bf2f(u16 v) {
    return __uint_as_float(((unsigned)v) << 16);
}

// global -> LDS direct, 16B per lane. LDS dest: wave-uniform base + lane*16.
#define GLOAD16(gsrc, ldst) \
    __builtin_amdgcn_global_load_lds((const __attribute__((address_space(1))) unsigned int*)(gsrc), \
                                     (__attribute__((address_space(3))) unsigned int*)(ldst), 16, 0, 0)

// ---------------------------------------------------------------------------
// K0: fused weight prep.
//  bid<256:  up_w [c][o][i][j] fp32 -> Wb bf16 [n=(o*4+i)*4+j][c]
//  bid>=256: pih_w [o][ci][3][3]  -> Bpack bf16 MFMA fragment order
__global__ __launch_bounds__(256) void prep_k(const float* __restrict__ uw,
                                              const float* __restrict__ pw,
                                              u16* __restrict__ Wb,
                                              u16* __restrict__ Bpack) {
    int bid = blockIdx.x;
    if (bid < 256) {
        int idx = bid * 256 + threadIdx.x;      // 0..65535
        int c = idx & 63;
        int n = idx >> 6;                       // (o,i,j)
        int o = n >> 4, i = (n >> 2) & 3, j = n & 3;
        Wb[idx] = f2bf(uw[((c * 64 + o) * 4 + i) * 4 + j]);
    } else {
        int idx = (bid - 256) * 256 + threadIdx.x;  // 0..36863
        if (idx >= 36864) return;
        int e = idx & 7, l = (idx >> 3) & 63, nf = (idx >> 9) & 3, s = idx >> 11;
        int ch = s & 1, kd = s >> 1;
        int dy = kd / 3, dx = kd % 3;
        int o  = nf * 16 + (l & 15);
        int ci = ch * 32 + (l >> 4) * 8 + e;
        Bpack[idx] = f2bf(pw[((o * 64 + ci) * 3 + dy) * 3 + dx]);
    }
}

// ---------------------------------------------------------------------------
// K0b: W fp32 [K][N] -> WT bf16 [N][K]  (tiled 64x64 transpose)
__global__ __launch_bounds__(256) void transWb_k(const float* __restrict__ W,
                                                 u16* __restrict__ WTb) {
    __shared__ float tile[64 * 65];
    int k0 = blockIdx.x * 64;
    int n0 = blockIdx.y * 64;
    int t = threadIdx.x;
#pragma unroll
    for (int i = 0; i < 4; ++i) {
        int idx = t + i * 256;                 // float4 id 0..1023
        int r  = idx >> 4;                     // k row
        int c4 = (idx & 15) * 4;               // n col
        float4 v = *(const float4*)&W[(long)(k0 + r) * 4096 + n0 + c4];
        tile[(c4 + 0) * 65 + r] = v.x;
        tile[(c4 + 1) * 65 + r] = v.y;
        tile[(c4 + 2) * 65 + r] = v.z;
        tile[(c4 + 3) * 65 + r] = v.w;
    }
    __syncthreads();
#pragma unroll
    for (int i = 0; i < 2; ++i) {
        int chunk = t + i * 256;               // 0..511
        int nr = chunk >> 3;
        int kc = (chunk & 7) * 8;
        u16x8 o;
#pragma unroll
        for (int j = 0; j < 8; ++j) o[j] = f2bf(tile[nr * 65 + kc + j]);
        *(u16x8*)&WTb[(long)(n0 + nr) * 4096 + k0 + kc] = o;
    }
}

// ---------------------------------------------------------------------------
// K1: maxpool 4x4 stride 4.  x[8,64,256,256] -> xp[8,64,64,64]
__global__ __launch_bounds__(256) void maxpool_k(const float* __restrict__ x,
                                                 float* __restrict__ xp) {
    int idx = blockIdx.x * 256 + threadIdx.x;
    int ox = idx & 63;
    int oy = (idx >> 6) & 63;
    int bc = idx >> 12;
    const float* p = x + ((long)bc * 256 + oy * 4) * 256 + ox * 4;
    float m = -3.4e38f;
#pragma unroll
    for (int r = 0; r < 4; ++r) {
        float4 v = *(const float4*)(p + r * 256);
        m = fmaxf(m, fmaxf(fmaxf(v.x, v.y), fmaxf(v.z, v.w)));
    }
    xp[idx] = m;
}

// ---------------------------------------------------------------------------
// K1b: xp NCHW fp32 -> xpc NHWC bf16 (per (b,y) row; LDS-tiled transpose)
__global__ __launch_bounds__(256) void nhwc_k(const float* __restrict__ xp,
                                              u16* __restrict__ xpc) {
    __shared__ float tile[64 * 65];
    int bid = blockIdx.x;                       // 512: b = bid>>6, y = bid&63
    int b = bid >> 6, y = bid & 63;
    int t = threadIdx.x;
#pragma unroll
    for (int i = 0; i < 4; ++i) {
        int fid = i * 256 + t;                  // 0..1023
        int c = fid >> 4, x4 = (fid & 15) * 4;
        float4 v = *(const float4*)&xp[(((long)(b * 64 + c) * 64) + y) * 64 + x4];
        tile[c * 65 + x4 + 0] = v.x;
        tile[c * 65 + x4 + 1] = v.y;
        tile[c * 65 + x4 + 2] = v.z;
        tile[c * 65 + x4 + 3] = v.w;
    }
    __syncthreads();
#pragma unroll
    for (int j = 0; j < 2; ++j) {
        int o = j * 256 + t;                    // 0..511
        int x = o >> 3, c8 = o & 7;
        u16x8 ov;
#pragma unroll
        for (int e = 0; e < 8; ++e) ov[e] = f2bf(tile[(c8 * 8 + e) * 65 + x]);
        *(u16x8*)&xpc[((long)(b * 64 + y) * 64 + x) * 64 + c8 * 8] = ov;
    }
}

// ---------------------------------------------------------------------------
// K2: conv3x3 as implicit-GEMM MFMA.  M=row of 64 px, N=64 oc, K=576.
__global__ __launch_bounds__(256) void conv_mfma_k(const u16* __restrict__ xpc,
                                                   const u16* __restrict__ Bpack,
                                                   const float* __restrict__ pb,
                                                   float* __restrict__ xpih) {
    __shared__ alignas(16) u16 ldsIn[3 * 66 * 64];   // 25344 B
    int bid = blockIdx.x;
    int b = bid >> 6, y = bid & 63;
    int t = threadIdx.x;
    int w = t >> 6, l = t & 63;
    int lr = l & 15, ksub = l >> 4;

    if (t < 48) {
        int r = t >> 4, q = t & 15;
        int off = r * 8448 + (q < 8 ? q * 16 : 8320 + (q - 8) * 16);
        *(u16x8*)((char*)ldsIn + off) = (u16x8){0, 0, 0, 0, 0, 0, 0, 0};
    }
#pragma unroll
    for (int i = 0; i < 6; ++i) {
        int r  = i >> 1;
        int ya = y - 1 + r;
        int wro = (i & 1) * 4096 + t * 16;      // within-row byte 0..8191
        int dst = r * 8448 + 128 + wro;
        if (ya >= 0 && ya < 64) {
            int xsl = 1 + (wro >> 7);
            int srcoff = (wro & ~127) | ((wro & 127) ^ ((xsl & 7) << 4));
            GLOAD16((const char*)xpc + (long)(b * 64 + ya) * 8192 + srcoff,
                    (char*)ldsIn + dst);
        } else {
            *(u16x8*)((char*)ldsIn + dst) = (u16x8){0, 0, 0, 0, 0, 0, 0, 0};
        }
    }
    __syncthreads();

    f32x4 acc[4];
#pragma unroll
    for (int mf = 0; mf < 4; ++mf) acc[mf] = (f32x4){0.f, 0.f, 0.f, 0.f};

#pragma unroll
    for (int kd = 0; kd < 9; ++kd) {
        int dy = kd / 3, dx = kd % 3;
#pragma unroll
        for (int ch = 0; ch < 2; ++ch) {
            int s = kd * 2 + ch;
            s16x8 bfrag = *(const s16x8*)(Bpack + ((s * 4 + w) * 64 + l) * 8);
#pragma unroll
            for (int mf = 0; mf < 4; ++mf) {
                int xsl  = mf * 16 + lr + dx;
                int coff = (ch * 64 + ksub * 16) ^ ((xsl & 7) << 4);
                s16x8 af = *(const s16x8*)((const char*)ldsIn +
                                           dy * 8448 + xsl * 128 + coff);
                acc[mf] = __builtin_amdgcn_mfma_f32_16x16x32_bf16(
                    af, bfrag, acc[mf], 0, 0, 0);
            }
        }
    }
    int o = w * 16 + lr;
    float bias = pb[o];
    float* dst = xpih + ((long)(b * 64 + o) * 64 + y) * 64;
#pragma unroll
    for (int mf = 0; mf < 4; ++mf)
#pragma unroll
        for (int r = 0; r < 4; ++r) {
            int x = mf * 16 + ksub * 4 + r;
            dst[x] = fmaxf(acc[mf][r] + bias, 0.f);
        }
}

// ---------------------------------------------------------------------------
// K3: Gram G[b][c][d] += sum_n xpih[c][n]*xpih[d][n]
__global__ __launch_bounds__(256) void gram_k(const float* __restrict__ xpih,
                                              float* __restrict__ G) {
    __shared__ float xs[64][132];
    int n0 = blockIdx.x * 128;
    int b  = blockIdx.y;
    int t = threadIdx.x;
#pragma unroll
    for (int l = 0; l < 8; ++l) {
        int f = t + l * 256;
        int row = f >> 5;
        int c4  = (f & 31) * 4;
        float4 v = *(const float4*)&xpih[(b * 64 + row) * NN + n0 + c4];
        *(float4*)&xs[row][c4] = v;
    }
    __syncthreads();
    int td4 = (t & 15) * 4;
    int tc4 = (t >> 4) * 4;
    float acc[4][4];
#pragma unroll
    for (int i = 0; i < 4; ++i)
#pragma unroll
        for (int j = 0; j < 4; ++j) acc[i][j] = 0.f;
#pragma unroll 4
    for (int nn = 0; nn < 128; ++nn) {
        float a0 = xs[tc4 + 0][nn], a1 = xs[tc4 + 1][nn];
        float a2 = xs[tc4 + 2][nn], a3 = xs[tc4 + 3][nn];
        float b0 = xs[td4 + 0][nn], b1 = xs[td4 + 1][nn];
        float b2 = xs[td4 + 2][nn], b3 = xs[td4 + 3][nn];
        acc[0][0] += a0 * b0; acc[0][1] += a0 * b1; acc[0][2] += a0 * b2; acc[0][3] += a0 * b3;
        acc[1][0] += a1 * b0; acc[1][1] += a1 * b1; acc[1][2] += a1 * b2; acc[1][3] += a1 * b3;
        acc[2][0] += a2 * b0; acc[2][1] += a2 * b1; acc[2][2] += a2 * b2; acc[2][3] += a2 * b3;
        acc[3][0] += a3 * b0; acc[3][1] += a3 * b1; acc[3][2] += a3 * b2; acc[3][3] += a3 * b3;
    }
    float* Gb = G + b * 4096;
#pragma unroll
    for (int i = 0; i < 4; ++i)
#pragma unroll
        for (int j = 0; j < 4; ++j)
            atomicAdd(&Gb[(tc4 + i) * 64 + td4 + j], acc[i][j]);
}

// ---------------------------------------------------------------------------
// K4: build L (transposed): LT[b][d][c] = (c==d) - d_c * A_cd * d_d
__global__ void build_L_k(const float* __restrict__ G, float* __restrict__ LT) {
    int b = blockIdx.x;
    int c = threadIdx.x;
    __shared__ float nrm[64], dvv[64];
    const float* Gb = G + b * 4096;
    float n = sqrtf(Gb[c * 64 + c]);
    n = fmaxf(n, 1e-12f);
    nrm[c] = n;
    __syncthreads();
    float rs = 0.f;
    for (int d = 0; d < 64; ++d) rs += Gb[c * 64 + d] / (n * nrm[d]);
    float dd = 1.0f / sqrtf(rs + 1e-8f);
    if (!(dd <= 3.0e38f)) dd = 0.0f;
    dvv[c] = dd;
    __syncthreads();
    for (int d = 0; d < 64; ++d) {
        float A = Gb[c * 64 + d] / (n * nrm[d]);
        float val = ((c == d) ? 1.0f : 0.0f) - dd * A * dvv[d];
        LT[b * 4096 + d * 64 + c] = val;
    }
}

// ---------------------------------------------------------------------------
// K5: out1[b][c][n] = sum_d L[c][d] * xp[d][n]  -> bf16 (GEMM A operand)
__global__ __launch_bounds__(256) void diffuse_k(const float* __restrict__ LT,
                                                 const float* __restrict__ xp,
                                                 u16* __restrict__ out1) {
    int b = blockIdx.y;
    int n = blockIdx.x * 256 + threadIdx.x;
    const float* Lb = LT + b * 4096;
    float acc[64];
#pragma unroll
    for (int c = 0; c < 64; ++c) acc[c] = 0.f;
    for (int d = 0; d < 64; ++d) {
        float v = xp[(b * 64 + d) * NN + n];
        const float* lp = Lb + d * 64;
#pragma unroll
        for (int c = 0; c < 64; ++c) acc[c] += lp[c] * v;
    }
#pragma unroll
    for (int c = 0; c < 64; ++c) out1[(b * 64 + c) * NN + n] = f2bf(acc[c]);
}

// ---------------------------------------------------------------------------
// K6: bf16 MFMA GEMM, 2-phase double-buffered (T3-min).
// Cp[z][512][4096](bf16) = A[512][4096] @ WT^T per K-slice of 1024.
#define KSPLIT 4
#define KSLICE 1024
__global__ __launch_bounds__(256) void gemm_mfma_k(const u16* __restrict__ A,
                                                   const u16* __restrict__ WT,
                                                   u16* __restrict__ Cp) {
    __shared__ alignas(16) u16 ldsA[2][8192];   // 2 x 16 KB
    __shared__ alignas(16) u16 ldsB[2][8192];
    int bid = blockIdx.x;                    // 512 blocks
    int swz = (bid & 7) * 64 + (bid >> 3);   // XCD-chunked (512 % 8 == 0)
    int m0 = (swz & 3) * 128;
    int n0 = ((swz >> 2) & 31) * 128;
    int z  = swz >> 7;
    int t = threadIdx.x;
    int w = t >> 6, l = t & 63;
    int wr = w >> 1, wc = w & 1;
    int lr = l & 15;                         // fragment row/col lane
    int lk = (l >> 4) << 4;                  // k-byte subgroup {0,16,32,48}

    f32x4 acc[4][4];
#pragma unroll
    for (int mf = 0; mf < 4; ++mf)
#pragma unroll
        for (int nf = 0; nf < 4; ++nf) acc[mf][nf] = (f32x4){0.f, 0.f, 0.f, 0.f};

    const char* Ab = (const char*)(A  + (long)m0 * 4096 + z * KSLICE);
    const char* Bb = (const char*)(WT + (long)n0 * 4096 + z * KSLICE);

    auto stage = [&](int buf, int k0) {
#pragma unroll
        for (int i = 0; i < 4; ++i) {
            int d   = i * 4096 + t * 16;     // linear LDS byte dest
            int row = d >> 7;
            int off = d & 127;
            int sk  = off ^ ((row & 7) << 4);   // pre-swizzled global source
            GLOAD16(Ab + (long)row * 8192 + k0 * 2 + sk, (char*)ldsA[buf] + d);
            GLOAD16(Bb + (long)row * 8192 + k0 * 2 + sk, (char*)ldsB[buf] + d);
        }
    };

    stage(0, 0);
    __syncthreads();                          // drains prologue loads
    int cur = 0;
    for (int k0 = 0; k0 < KSLICE; k0 += 64) {
        if (k0 + 64 < KSLICE) stage(cur ^ 1, k0 + 64);   // prefetch next tile
#pragma unroll
        for (int kk = 0; kk < 2; ++kk) {
            s16x8 af[4], bf[4];
#pragma unroll
            for (int f = 0; f < 4; ++f) {
                int ar = wr * 64 + f * 16 + lr;
                af[f] = *(const s16x8*)((const char*)ldsA[cur] + ar * 128 +
                                        ((kk * 64 + lk) ^ ((ar & 7) << 4)));
                int br = wc * 64 + f * 16 + lr;
                bf[f] = *(const s16x8*)((const char*)ldsB[cur] + br * 128 +
                                        ((kk * 64 + lk) ^ ((br & 7) << 4)));
            }
#pragma unroll
            for (int mf = 0; mf < 4; ++mf)
#pragma unroll
                for (int nf = 0; nf < 4; ++nf)
                    acc[mf][nf] = __builtin_amdgcn_mfma_f32_16x16x32_bf16(
                        af[mf], bf[nf], acc[mf][nf], 0, 0, 0);
        }
        __syncthreads();                      // drains prefetch; next buf ready
        cur ^= 1;
    }
    // epilogue: C/D layout col=lane&15, row=(lane>>4)*4+reg
    u16* Cz = Cp + (long)z * 2097152;
#pragma unroll
    for (int mf = 0; mf < 4; ++mf)
#pragma unroll
        for (int nf = 0; nf < 4; ++nf)
#pragma unroll
            for (int r = 0; r < 4; ++r) {
                int row = m0 + wr * 64 + mf * 16 + (l >> 4) * 4 + r;
                int col = n0 + wc * 64 + nf * 16 + lr;
                Cz[(long)row * 4096 + col] = f2bf(acc[mf][nf][r]);
            }
}

// ---------------------------------------------------------------------------
// K6b: A2[b*4096+n][c] (bf16) = sum_z Cp[z][b*64+c][n]   (reduce + transpose)
__global__ __launch_bounds__(256) void reduce4T_k(const u16* __restrict__ Cp,
                                                  u16* __restrict__ A2) {
    __shared__ float xs[64 * 65];
    int n0 = blockIdx.x * 64;
    int b  = blockIdx.y;
    int t = threadIdx.x;
    int c = t >> 2, seg = t & 3;
    float s[16];
#pragma unroll
    for (int k = 0; k < 16; ++k) s[k] = 0.f;
#pragma unroll
    for (int z = 0; z < KSPLIT; ++z) {
        const u16* p = Cp + ((long)z * 512 + b * 64 + c) * 4096 + n0 + seg * 16;
        u16x8 v0 = *(const u16x8*)p;
        u16x8 v1 = *(const u16x8*)(p + 8);
#pragma unroll
        for (int k = 0; k < 8; ++k) {
            s[k]     += bf2f(v0[k]);
            s[8 + k] += bf2f(v1[k]);
        }
    }
#pragma unroll
    for (int k = 0; k < 16; ++k) xs[c * 65 + seg * 16 + k] = s[k];
    __syncthreads();
    int n = t >> 2, q = t & 3;
    u16x8 o0, o1;
#pragma unroll
    for (int k = 0; k < 8; ++k) o0[k] = f2bf(xs[(q * 16 + k) * 65 + n]);
#pragma unroll
    for (int k = 0; k < 8; ++k) o1[k] = f2bf(xs[(q * 16 + 8 + k) * 65 + n]);
    u16* dst = A2 + ((long)b * 4096 + n0 + n) * 64 + q * 16;
    *(u16x8*)dst = o0;
    *(u16x8*)(dst + 8) = o1;
}

// ---------------------------------------------------------------------------
// K7: convT as MFMA GEMM with LDS-bounced, fully-coalesced epilogue.
// C[m=32768(b,h,w)][n=1024(o,i,j)] = A2 @ Wb^T, K=64.
// out[b,o,4h+i,4w+j] = relu(C + up_b[o] + x[same]); float4 I/O per lane.
__global__ __launch_bounds__(256) void convT_mfma_k(const u16* __restrict__ A2,
                                                    const u16* __restrict__ Wb,
                                                    const float* __restrict__ ub,
                                                    const float* __restrict__ x,
                                                    float* __restrict__ out) {
    __shared__ alignas(16) char smem[34816];     // staging 32KB | C-bounce 128x68 f32
    u16*   ldsA = (u16*)smem;                    // 16 KB
    u16*   ldsB = (u16*)(smem + 16384);          // 16 KB
    float* ldsC = (float*)smem;
    int mt = blockIdx.x;                         // 0..255
    int nt = blockIdx.y;                         // 0..7
    int m0 = mt * 128;
    int n0 = nt * 128;
    int t = threadIdx.x;
    int w = t >> 6, l = t & 63;
    int wr = w >> 1, wc = w & 1;
    int lr = l & 15;
    int lkb = (l >> 4) << 4;                     // k-byte subgroup {0,16,32,48}

    const char* Ab = (const char*)(A2 + (long)m0 * 64);
    const char* Bb = (const char*)(Wb + (long)n0 * 64);
#pragma unroll
    for (int i = 0; i < 4; ++i) {
        int d = i * 4096 + t * 16;
        int srcoff = (d & ~127) | ((d & 127) ^ (((d >> 7) & 7) << 4));
        GLOAD16(Ab + srcoff, (char*)ldsA + d);
        GLOAD16(Bb + srcoff, (char*)ldsB + d);
    }
    __syncthreads();

    f32x4 acc[4][4];
#pragma unroll
    for (int mf = 0; mf < 4; ++mf)
#pragma unroll
        for (int nf = 0; nf < 4; ++nf) acc[mf][nf] = (f32x4){0.f, 0.f, 0.f, 0.f};

#pragma unroll
    for (int kk = 0; kk < 2; ++kk) {
        s16x8 af[4], bfg[4];
#pragma unroll
        for (int f = 0; f < 4; ++f) {
            int ar = wr * 64 + f * 16 + lr;
            af[f] = *(const s16x8*)((const char*)ldsA + ar * 128 +
                                    ((kk * 64 + lkb) ^ ((ar & 7) << 4)));
            int br = wc * 64 + f * 16 + lr;
            bfg[f] = *(const s16x8*)((const char*)ldsB + br * 128 +
                                     ((kk * 64 + lkb) ^ ((br & 7) << 4)));
        }
#pragma unroll
        for (int mf = 0; mf < 4; ++mf)
#pragma unroll
            for (int nf = 0; nf < 4; ++nf)
                acc[mf][nf] = __builtin_amdgcn_mfma_f32_16x16x32_bf16(
                    af[mf], bfg[nf], acc[mf][nf], 0, 0, 0);
    }
    __syncthreads();                             // ldsA/B dead; reuse as ldsC

    // two rounds over n-halves: bounce C through LDS, then float4 I/O
#pragma unroll
    for (int nh = 0; nh < 2; ++nh) {
        if (nh) __syncthreads();                 // protect round-0 reads
        if (wc == nh) {
#pragma unroll
            for (int mf = 0; mf < 4; ++mf)
#pragma unroll
                for (int nf = 0; nf < 4; ++nf)
#pragma unroll
                    for (int r = 0; r < 4; ++r) {
                        int row = wr * 64 + mf * 16 + (l >> 4) * 4 + r;
                        int col = nf * 16 + lr;
                        ldsC[row * 68 + (col ^ (((row >> 3) & 7) << 2))] =
                            acc[mf][nf][r];
                    }
        }
        __syncthreads();
#pragma unroll
        for (int q = 0; q < 2; ++q) {
            int idx = q * 256 + t;               // 0..511 = 128 m x 4 oo
            int ml = idx & 127;
            int oo = idx >> 7;                   // wave-uniform
            int o  = nt * 8 + nh * 4 + oo;
            float bias = ub[o];
            int mg = m0 + ml;
            int b = mg >> 12, pix = mg & 4095;
            int h = pix >> 6, ww = pix & 63;
            long base = ((long)(b * 64 + o) * 256 + h * 4) * 256 + ww * 4;
#pragma unroll
            for (int i = 0; i < 4; ++i) {
                f32x4 cv = *(const f32x4*)&ldsC[ml * 68 +
                            ((oo * 16 + i * 4) ^ (((ml >> 3) & 7) << 2))];
                float4 xi = *(const float4*)&x[base + i * 256];
                float4 rr;
                rr.x = fmaxf(cv[0] + bias + xi.x, 0.f);
                rr.y = fmaxf(cv[1] + bias + xi.y, 0.f);
                rr.z = fmaxf(cv[2] + bias + xi.z, 0.f);
                rr.w = fmaxf(cv[3] + bias + xi.w, 0.f);
                *(float4*)&out[base + i * 256] = rr;
            }
        }
    }
}

// ---------------------------------------------------------------------------
extern "C" void kernel_launch(void* const* d_in, const int* in_sizes, int n_in,
                              void* d_out, int out_size, void* d_ws, size_t ws_size,
                              hipStream_t stream) {
    const float* x      = (const float*)d_in[0];
    const float* weight = (const float*)d_in[1];
    const float* pih_w  = (const float*)d_in[2];
    const float* pih_b  = (const float*)d_in[3];
    const float* up_w   = (const float*)d_in[4];
    const float* up_b   = (const float*)d_in[5];
    float* out = (float*)d_out;
    float* ws  = (float*)d_ws;

    // workspace layout (float offsets)
    float* xp    = ws;                         // 2,097,152 f  (8,64,64,64)
    float* xpih  = ws + 2097152;               // 2,097,152 f  fp32 conv out
    float* G     = ws + 4194304;               // 32,768 f
    float* LT    = ws + 4227072;               // 32,768 f
    u16*   Wb    = (u16*)(ws + 4259840);       // 65,536 u16 (convT B^T bf16)
    u16*   WTb   = (u16*)(ws + 4325376);       // 16,777,216 u16: WT bf16 [4096][4096]
    u16*   Cp    = (u16*)(ws + 12713984);      // 8,388,608 u16: 4 bf16 partials
    u16*   Ab16  = (u16*)xpih;                 // A bf16 reuses xpih (dead after gram)
    u16*   A2    = (u16*)xp;                   // out2T bf16 reuses xp (dead after diffuse)
    // conv scratch aliases Cp region (dead until gemm_mfma_k writes it):
    u16*   xpc   = Cp;                         // 2,097,152 u16 NHWC bf16
    u16*   Bpack = Cp + 2097152;               // 36,864 u16 packed conv weights

    hipMemsetAsync(G, 0, 32768 * sizeof(float), stream);
    prep_k      <<<400, 256, 0, stream>>>(up_w, pih_w, Wb, Bpack);
    transWb_k   <<<dim3(64, 64), 256, 0, stream>>>(weight, WTb);
    maxpool_k   <<<8192, 256, 0, stream>>>(x, xp);
    nhwc_k      <<<512, 256, 0, stream>>>(xp, xpc);
    conv_mfma_k <<<512, 256, 0, stream>>>(xpc, Bpack, pih_b, xpih);
    gram_k      <<<dim3(32, 8), 256, 0, stream>>>(xpih, G);
    build_L_k   <<<8, 64, 0, stream>>>(G, LT);
    diffuse_k   <<<dim3(16, 8), 256, 0, stream>>>(LT, xp, Ab16);
    gemm_mfma_k <<<512, 256, 0, stream>>>(Ab16, WTb, Cp);
    reduce4T_k  <<<dim3(64, 8), 256, 0, stream>>>(Cp, A2);
    convT_mfma_k<<<dim3(256, 8), 256, 0, stream>>>(A2, Wb, up_b, x, out);
}

// Round 6
// 190.517 us; speedup vs baseline: 3.9197x; 1.0527x over previous
//
#include <hip/hip_runtime.h>

// Problem constants: b=8, c=64, hw=256, RATIO=4, HP=WP=64, N=4096.
#define NB 8
#define NC 64
#define HW 256
#define HP 64
#define NN 4096   // HP*WP

typedef unsigned short u16;
typedef unsigned int u32;
typedef __attribute__((ext_vector_type(8))) short s16x8;          // MFMA a/b frag (8 bf16)
typedef __attribute__((ext_vector_type(8))) unsigned short u16x8; // 16B bf16 vector
typedef __attribute__((ext_vector_type(4))) float f32x4;          // MFMA acc

__device__ __forceinline__ u16 f2bf(float f) {          // fp32 -> bf16 RNE
    unsigned u = __float_as_uint(f);
    return (u16)((u + 0x7fffu + ((u >> 16) & 1u)) >> 16);
}
__device__ __forceinline__ float bf2f(u16 v) {
    return __uint_as_float(((unsigned)v) << 16);
}

// global -> LDS direct, 16B per lane. LDS dest: wave-uniform base + lane*16.
#define GLOAD16(gsrc, ldst) \
    __builtin_amdgcn_global_load_lds((const __attribute__((address_space(1))) unsigned int*)(gsrc), \
                                     (__attribute__((address_space(3))) unsigned int*)(ldst), 16, 0, 0)

// ---------------------------------------------------------------------------
// K0: fused weight prep.
//  bid<256:  up_w [c][o][i][j] fp32 -> Wb bf16 [n=(o*4+i)*4+j][c]
//  bid>=256: pih_w [o][ci][3][3]  -> Bpack bf16 MFMA fragment order
__global__ __launch_bounds__(256) void prep_k(const float* __restrict__ uw,
                                              const float* __restrict__ pw,
                                              u16* __restrict__ Wb,
                                              u16* __restrict__ Bpack) {
    int bid = blockIdx.x;
    if (bid < 256) {
        int idx = bid * 256 + threadIdx.x;      // 0..65535
        int c = idx & 63;
        int n = idx >> 6;                       // (o,i,j)
        int o = n >> 4, i = (n >> 2) & 3, j = n & 3;
        Wb[idx] = f2bf(uw[((c * 64 + o) * 4 + i) * 4 + j]);
    } else {
        int idx = (bid - 256) * 256 + threadIdx.x;  // 0..36863
        if (idx >= 36864) return;
        int e = idx & 7, l = (idx >> 3) & 63, nf = (idx >> 9) & 3, s = idx >> 11;
        int ch = s & 1, kd = s >> 1;
        int dy = kd / 3, dx = kd % 3;
        int o  = nf * 16 + (l & 15);
        int ci = ch * 32 + (l >> 4) * 8 + e;
        Bpack[idx] = f2bf(pw[((o * 64 + ci) * 3 + dy) * 3 + dx]);
    }
}

// ---------------------------------------------------------------------------
// K0b: W fp32 [K][N] -> WT bf16 [N][K]  (tiled 64x64 transpose)
__global__ __launch_bounds__(256) void transWb_k(const float* __restrict__ W,
                                                 u16* __restrict__ WTb) {
    __shared__ float tile[64 * 65];
    int k0 = blockIdx.x * 64;
    int n0 = blockIdx.y * 64;
    int t = threadIdx.x;
#pragma unroll
    for (int i = 0; i < 4; ++i) {
        int idx = t + i * 256;                 // float4 id 0..1023
        int r  = idx >> 4;                     // k row
        int c4 = (idx & 15) * 4;               // n col
        float4 v = *(const float4*)&W[(long)(k0 + r) * 4096 + n0 + c4];
        tile[(c4 + 0) * 65 + r] = v.x;
        tile[(c4 + 1) * 65 + r] = v.y;
        tile[(c4 + 2) * 65 + r] = v.z;
        tile[(c4 + 3) * 65 + r] = v.w;
    }
    __syncthreads();
#pragma unroll
    for (int i = 0; i < 2; ++i) {
        int chunk = t + i * 256;               // 0..511
        int nr = chunk >> 3;
        int kc = (chunk & 7) * 8;
        u16x8 o;
#pragma unroll
        for (int j = 0; j < 8; ++j) o[j] = f2bf(tile[nr * 65 + kc + j]);
        *(u16x8*)&WTb[(long)(n0 + nr) * 4096 + k0 + kc] = o;
    }
}

// ---------------------------------------------------------------------------
// K1: maxpool 4x4 s4 + NCHW->NHWC + bf16.  x[8,64,256,256] -> xpc[b][y][x][c]
// Block = (b,y): reads x[b,:,4y..4y+4,:] (256 KB), writes one 8 KB xpc row-slab.
__global__ __launch_bounds__(256) void maxpool_nhwc_k(const float* __restrict__ x,
                                                      u16* __restrict__ xpc) {
    __shared__ u16 tile[64 * 66];               // [c][x] stride 66
    int bid = blockIdx.x;                       // 512
    int b = bid >> 6, y = bid & 63;
    int t = threadIdx.x;
    int c = t >> 2, q = t & 3;
    const float* p = x + ((long)(b * 64 + c) * 256 + y * 4) * 256 + q * 64;
#pragma unroll
    for (int i = 0; i < 16; ++i) {
        float m = -3.4e38f;
#pragma unroll
        for (int r = 0; r < 4; ++r) {
            float4 v = *(const float4*)(p + r * 256 + i * 4);
            m = fmaxf(m, fmaxf(fmaxf(v.x, v.y), fmaxf(v.z, v.w)));
        }
        tile[c * 66 + q * 16 + i] = f2bf(m);
    }
    __syncthreads();
    int xo = t >> 2, cp = t & 3;
    u16x8 o0, o1;
#pragma unroll
    for (int e = 0; e < 8; ++e) o0[e] = tile[(cp * 16 + e) * 66 + xo];
#pragma unroll
    for (int e = 0; e < 8; ++e) o1[e] = tile[(cp * 16 + 8 + e) * 66 + xo];
    u16* dst = xpc + ((long)(b * 4096 + y * 64 + xo)) * 64 + cp * 16;
    *(u16x8*)dst = o0;
    *(u16x8*)(dst + 8) = o1;
}

// ---------------------------------------------------------------------------
// K2: conv3x3 as implicit-GEMM MFMA -> xpihb bf16 [b*64+o][n=y*64+x]
__global__ __launch_bounds__(256) void conv_mfma_k(const u16* __restrict__ xpc,
                                                   const u16* __restrict__ Bpack,
                                                   const float* __restrict__ pb,
                                                   u16* __restrict__ xpihb) {
    __shared__ alignas(16) u16 ldsIn[3 * 66 * 64];   // 25344 B
    int bid = blockIdx.x;
    int b = bid >> 6, y = bid & 63;
    int t = threadIdx.x;
    int w = t >> 6, l = t & 63;
    int lr = l & 15, ksub = l >> 4;

    if (t < 48) {
        int r = t >> 4, q = t & 15;
        int off = r * 8448 + (q < 8 ? q * 16 : 8320 + (q - 8) * 16);
        *(u16x8*)((char*)ldsIn + off) = (u16x8){0, 0, 0, 0, 0, 0, 0, 0};
    }
#pragma unroll
    for (int i = 0; i < 6; ++i) {
        int r  = i >> 1;
        int ya = y - 1 + r;
        int wro = (i & 1) * 4096 + t * 16;      // within-row byte 0..8191
        int dst = r * 8448 + 128 + wro;
        if (ya >= 0 && ya < 64) {
            int xsl = 1 + (wro >> 7);
            int srcoff = (wro & ~127) | ((wro & 127) ^ ((xsl & 7) << 4));
            GLOAD16((const char*)xpc + (long)(b * 64 + ya) * 8192 + srcoff,
                    (char*)ldsIn + dst);
        } else {
            *(u16x8*)((char*)ldsIn + dst) = (u16x8){0, 0, 0, 0, 0, 0, 0, 0};
        }
    }
    __syncthreads();

    f32x4 acc[4];
#pragma unroll
    for (int mf = 0; mf < 4; ++mf) acc[mf] = (f32x4){0.f, 0.f, 0.f, 0.f};

#pragma unroll
    for (int kd = 0; kd < 9; ++kd) {
        int dy = kd / 3, dx = kd % 3;
#pragma unroll
        for (int ch = 0; ch < 2; ++ch) {
            int s = kd * 2 + ch;
            s16x8 bfrag = *(const s16x8*)(Bpack + ((s * 4 + w) * 64 + l) * 8);
#pragma unroll
            for (int mf = 0; mf < 4; ++mf) {
                int xsl  = mf * 16 + lr + dx;
                int coff = (ch * 64 + ksub * 16) ^ ((xsl & 7) << 4);
                s16x8 af = *(const s16x8*)((const char*)ldsIn +
                                           dy * 8448 + xsl * 128 + coff);
                acc[mf] = __builtin_amdgcn_mfma_f32_16x16x32_bf16(
                    af, bfrag, acc[mf], 0, 0, 0);
            }
        }
    }
    int o = w * 16 + lr;
    float bias = pb[o];
    u16* dst = xpihb + ((long)(b * 64 + o)) * 4096 + y * 64;
#pragma unroll
    for (int mf = 0; mf < 4; ++mf)
#pragma unroll
        for (int rp = 0; rp < 2; ++rp) {
            u16 lo = f2bf(fmaxf(acc[mf][rp * 2]     + bias, 0.f));
            u16 hi = f2bf(fmaxf(acc[mf][rp * 2 + 1] + bias, 0.f));
            *(u32*)&dst[mf * 16 + ksub * 4 + rp * 2] = (u32)lo | ((u32)hi << 16);
        }
}

// ---------------------------------------------------------------------------
// K3: Gram via MFMA.  G[b] += X Xᵀ over n-chunk of 128 (X = xpihb rows).
// Both MFMA operands come from the same staged [64c][128n] tile.
__global__ __launch_bounds__(256) void gram_mfma_k(const u16* __restrict__ xpihb,
                                                   float* __restrict__ G) {
    __shared__ alignas(16) u16 lds[64 * 128];    // 16 KB, 256 B rows
    int n0 = blockIdx.x * 128;
    int b  = blockIdx.y;
    int t = threadIdx.x;
    int w = t >> 6, l = t & 63;
    int lr = l & 15, ksub = l >> 4;
#pragma unroll
    for (int i = 0; i < 4; ++i) {
        int d = i * 4096 + t * 16;
        int row = d >> 8, off = d & 255;
        GLOAD16((const char*)xpihb + ((long)(b * 64 + row)) * 8192 + n0 * 2 +
                (off ^ ((row & 15) << 4)),
                (char*)lds + d);
    }
    __syncthreads();

    f32x4 acc[4];
#pragma unroll
    for (int mf = 0; mf < 4; ++mf) acc[mf] = (f32x4){0.f, 0.f, 0.f, 0.f};
#pragma unroll
    for (int kk = 0; kk < 4; ++kk) {
        int brow = w * 16 + lr;
        s16x8 bf = *(const s16x8*)((const char*)lds + brow * 256 +
                                   ((kk * 64 + ksub * 16) ^ ((brow & 15) << 4)));
#pragma unroll
        for (int mf = 0; mf < 4; ++mf) {
            int arow = mf * 16 + lr;
            s16x8 af = *(const s16x8*)((const char*)lds + arow * 256 +
                                       ((kk * 64 + ksub * 16) ^ ((arow & 15) << 4)));
            acc[mf] = __builtin_amdgcn_mfma_f32_16x16x32_bf16(af, bf, acc[mf], 0, 0, 0);
        }
    }
    float* Gb = G + b * 4096;
#pragma unroll
    for (int mf = 0; mf < 4; ++mf)
#pragma unroll
        for (int r = 0; r < 4; ++r)
            atomicAdd(&Gb[(mf * 16 + (l >> 4) * 4 + r) * 64 + w * 16 + lr],
                      acc[mf][r]);
}

// ---------------------------------------------------------------------------
// K4: build L -> Lb16 bf16 row-major [b][c][d]
__global__ void build_L_k(const float* __restrict__ G, u16* __restrict__ Lb16) {
    int b = blockIdx.x;
    int c = threadIdx.x;
    __shared__ float nrm[64], dvv[64];
    const float* Gb = G + b * 4096;
    float n = sqrtf(Gb[c * 64 + c]);
    n = fmaxf(n, 1e-12f);
    nrm[c] = n;
    __syncthreads();
    float rs = 0.f;
    for (int d = 0; d < 64; ++d) rs += Gb[c * 64 + d] / (n * nrm[d]);
    float dd = 1.0f / sqrtf(rs + 1e-8f);
    if (!(dd <= 3.0e38f)) dd = 0.0f;
    dvv[c] = dd;
    __syncthreads();
    for (int d = 0; d < 64; ++d) {
        float A = Gb[c * 64 + d] / (n * nrm[d]);
        float val = ((c == d) ? 1.0f : 0.0f) - dd * A * dvv[d];
        Lb16[(b * 64 + c) * 64 + d] = f2bf(val);
    }
}

// ---------------------------------------------------------------------------
// K5: diffuse via MFMA.  Ab16[b*64+c][n] = sum_d L[c][d] * xp[d][n].
// A-frags read Lb16 rows direct from global (L2-hot); B staged from xpc NHWC.
__global__ __launch_bounds__(256) void diffuse_mfma_k(const u16* __restrict__ Lb16,
                                                      const u16* __restrict__ xpc,
                                                      u16* __restrict__ Ab16) {
    __shared__ alignas(16) u16 lds[128 * 64];    // 16 KB, 128 B rows
    int n0 = blockIdx.x * 128;
    int b  = blockIdx.y;
    int t = threadIdx.x;
    int w = t >> 6, l = t & 63;
    int lr = l & 15, ksub = l >> 4;
#pragma unroll
    for (int i = 0; i < 4; ++i) {
        int d = i * 4096 + t * 16;
        int row = d >> 7, off = d & 127;
        GLOAD16((const char*)xpc + ((long)(b * 4096 + n0 + row)) * 128 +
                (off ^ ((row & 7) << 4)),
                (char*)lds + d);
    }
    __syncthreads();

    const u16* Lb = Lb16 + b * 4096;
    f32x4 acc[4][2];
#pragma unroll
    for (int mf = 0; mf < 4; ++mf)
#pragma unroll
        for (int nq = 0; nq < 2; ++nq) acc[mf][nq] = (f32x4){0.f, 0.f, 0.f, 0.f};

#pragma unroll
    for (int kk = 0; kk < 2; ++kk) {
        s16x8 bfr[2];
#pragma unroll
        for (int nq = 0; nq < 2; ++nq) {
            int brow = w * 32 + nq * 16 + lr;
            bfr[nq] = *(const s16x8*)((const char*)lds + brow * 128 +
                                      ((kk * 64 + ksub * 16) ^ ((brow & 7) << 4)));
        }
#pragma unroll
        for (int mf = 0; mf < 4; ++mf) {
            s16x8 af = *(const s16x8*)(Lb + (mf * 16 + lr) * 64 + kk * 32 + ksub * 8);
#pragma unroll
            for (int nq = 0; nq < 2; ++nq)
                acc[mf][nq] = __builtin_amdgcn_mfma_f32_16x16x32_bf16(
                    af, bfr[nq], acc[mf][nq], 0, 0, 0);
        }
    }
#pragma unroll
    for (int mf = 0; mf < 4; ++mf)
#pragma unroll
        for (int nq = 0; nq < 2; ++nq)
#pragma unroll
            for (int r = 0; r < 4; ++r)
                Ab16[((long)(b * 64 + mf * 16 + (l >> 4) * 4 + r)) * 4096 +
                     n0 + w * 32 + nq * 16 + lr] = f2bf(acc[mf][nq][r]);
}

// ---------------------------------------------------------------------------
// K6: bf16 MFMA GEMM, 2-phase double-buffered.
#define KSPLIT 4
#define KSLICE 1024
__global__ __launch_bounds__(256) void gemm_mfma_k(const u16* __restrict__ A,
                                                   const u16* __restrict__ WT,
                                                   u16* __restrict__ Cp) {
    __shared__ alignas(16) u16 ldsA[2][8192];   // 2 x 16 KB
    __shared__ alignas(16) u16 ldsB[2][8192];
    int bid = blockIdx.x;                    // 512 blocks
    int swz = (bid & 7) * 64 + (bid >> 3);   // XCD-chunked (512 % 8 == 0)
    int m0 = (swz & 3) * 128;
    int n0 = ((swz >> 2) & 31) * 128;
    int z  = swz >> 7;
    int t = threadIdx.x;
    int w = t >> 6, l = t & 63;
    int wr = w >> 1, wc = w & 1;
    int lr = l & 15;
    int lk = (l >> 4) << 4;

    f32x4 acc[4][4];
#pragma unroll
    for (int mf = 0; mf < 4; ++mf)
#pragma unroll
        for (int nf = 0; nf < 4; ++nf) acc[mf][nf] = (f32x4){0.f, 0.f, 0.f, 0.f};

    const char* Ab = (const char*)(A  + (long)m0 * 4096 + z * KSLICE);
    const char* Bb = (const char*)(WT + (long)n0 * 4096 + z * KSLICE);

    auto stage = [&](int buf, int k0) {
#pragma unroll
        for (int i = 0; i < 4; ++i) {
            int d   = i * 4096 + t * 16;
            int row = d >> 7;
            int off = d & 127;
            int sk  = off ^ ((row & 7) << 4);
            GLOAD16(Ab + (long)row * 8192 + k0 * 2 + sk, (char*)ldsA[buf] + d);
            GLOAD16(Bb + (long)row * 8192 + k0 * 2 + sk, (char*)ldsB[buf] + d);
        }
    };

    stage(0, 0);
    __syncthreads();
    int cur = 0;
    for (int k0 = 0; k0 < KSLICE; k0 += 64) {
        if (k0 + 64 < KSLICE) stage(cur ^ 1, k0 + 64);
#pragma unroll
        for (int kk = 0; kk < 2; ++kk) {
            s16x8 af[4], bf[4];
#pragma unroll
            for (int f = 0; f < 4; ++f) {
                int ar = wr * 64 + f * 16 + lr;
                af[f] = *(const s16x8*)((const char*)ldsA[cur] + ar * 128 +
                                        ((kk * 64 + lk) ^ ((ar & 7) << 4)));
                int br = wc * 64 + f * 16 + lr;
                bf[f] = *(const s16x8*)((const char*)ldsB[cur] + br * 128 +
                                        ((kk * 64 + lk) ^ ((br & 7) << 4)));
            }
#pragma unroll
            for (int mf = 0; mf < 4; ++mf)
#pragma unroll
                for (int nf = 0; nf < 4; ++nf)
                    acc[mf][nf] = __builtin_amdgcn_mfma_f32_16x16x32_bf16(
                        af[mf], bf[nf], acc[mf][nf], 0, 0, 0);
        }
        __syncthreads();
        cur ^= 1;
    }
    u16* Cz = Cp + (long)z * 2097152;
#pragma unroll
    for (int mf = 0; mf < 4; ++mf)
#pragma unroll
        for (int nf = 0; nf < 4; ++nf)
#pragma unroll
            for (int r = 0; r < 4; ++r) {
                int row = m0 + wr * 64 + mf * 16 + (l >> 4) * 4 + r;
                int col = n0 + wc * 64 + nf * 16 + lr;
                Cz[(long)row * 4096 + col] = f2bf(acc[mf][nf][r]);
            }
}

// ---------------------------------------------------------------------------
// K6b: A2[b*4096+n][c] (bf16) = sum_z Cp[z][b*64+c][n]   (reduce + transpose)
__global__ __launch_bounds__(256) void reduce4T_k(const u16* __restrict__ Cp,
                                                  u16* __restrict__ A2) {
    __shared__ float xs[64 * 65];
    int n0 = blockIdx.x * 64;
    int b  = blockIdx.y;
    int t = threadIdx.x;
    int c = t >> 2, seg = t & 3;
    float s[16];
#pragma unroll
    for (int k = 0; k < 16; ++k) s[k] = 0.f;
#pragma unroll
    for (int z = 0; z < KSPLIT; ++z) {
        const u16* p = Cp + ((long)z * 512 + b * 64 + c) * 4096 + n0 + seg * 16;
        u16x8 v0 = *(const u16x8*)p;
        u16x8 v1 = *(const u16x8*)(p + 8);
#pragma unroll
        for (int k = 0; k < 8; ++k) {
            s[k]     += bf2f(v0[k]);
            s[8 + k] += bf2f(v1[k]);
        }
    }
#pragma unroll
    for (int k = 0; k < 16; ++k) xs[c * 65 + seg * 16 + k] = s[k];
    __syncthreads();
    int n = t >> 2, q = t & 3;
    u16x8 o0, o1;
#pragma unroll
    for (int k = 0; k < 8; ++k) o0[k] = f2bf(xs[(q * 16 + k) * 65 + n]);
#pragma unroll
    for (int k = 0; k < 8; ++k) o1[k] = f2bf(xs[(q * 16 + 8 + k) * 65 + n]);
    u16* dst = A2 + ((long)b * 4096 + n0 + n) * 64 + q * 16;
    *(u16x8*)dst = o0;
    *(u16x8*)(dst + 8) = o1;
}

// ---------------------------------------------------------------------------
// K7: convT as MFMA GEMM with LDS-bounced, fully-coalesced epilogue.
__global__ __launch_bounds__(256) void convT_mfma_k(const u16* __restrict__ A2,
                                                    const u16* __restrict__ Wb,
                                                    const float* __restrict__ ub,
                                                    const float* __restrict__ x,
                                                    float* __restrict__ out) {
    __shared__ alignas(16) char smem[34816];     // staging 32KB | C-bounce 128x68 f32
    u16*   ldsA = (u16*)smem;
    u16*   ldsB = (u16*)(smem + 16384);
    float* ldsC = (float*)smem;
    int mt = blockIdx.x;
    int nt = blockIdx.y;
    int m0 = mt * 128;
    int n0 = nt * 128;
    int t = threadIdx.x;
    int w = t >> 6, l = t & 63;
    int wr = w >> 1, wc = w & 1;
    int lr = l & 15;
    int lkb = (l >> 4) << 4;

    const char* Ab = (const char*)(A2 + (long)m0 * 64);
    const char* Bb = (const char*)(Wb + (long)n0 * 64);
#pragma unroll
    for (int i = 0; i < 4; ++i) {
        int d = i * 4096 + t * 16;
        int srcoff = (d & ~127) | ((d & 127) ^ (((d >> 7) & 7) << 4));
        GLOAD16(Ab + srcoff, (char*)ldsA + d);
        GLOAD16(Bb + srcoff, (char*)ldsB + d);
    }
    __syncthreads();

    f32x4 acc[4][4];
#pragma unroll
    for (int mf = 0; mf < 4; ++mf)
#pragma unroll
        for (int nf = 0; nf < 4; ++nf) acc[mf][nf] = (f32x4){0.f, 0.f, 0.f, 0.f};

#pragma unroll
    for (int kk = 0; kk < 2; ++kk) {
        s16x8 af[4], bfg[4];
#pragma unroll
        for (int f = 0; f < 4; ++f) {
            int ar = wr * 64 + f * 16 + lr;
            af[f] = *(const s16x8*)((const char*)ldsA + ar * 128 +
                                    ((kk * 64 + lkb) ^ ((ar & 7) << 4)));
            int br = wc * 64 + f * 16 + lr;
            bfg[f] = *(const s16x8*)((const char*)ldsB + br * 128 +
                                     ((kk * 64 + lkb) ^ ((br & 7) << 4)));
        }
#pragma unroll
        for (int mf = 0; mf < 4; ++mf)
#pragma unroll
            for (int nf = 0; nf < 4; ++nf)
                acc[mf][nf] = __builtin_amdgcn_mfma_f32_16x16x32_bf16(
                    af[mf], bfg[nf], acc[mf][nf], 0, 0, 0);
    }
    __syncthreads();

#pragma unroll
    for (int nh = 0; nh < 2; ++nh) {
        if (nh) __syncthreads();
        if (wc == nh) {
#pragma unroll
            for (int mf = 0; mf < 4; ++mf)
#pragma unroll
                for (int nf = 0; nf < 4; ++nf)
#pragma unroll
                    for (int r = 0; r < 4; ++r) {
                        int row = wr * 64 + mf * 16 + (l >> 4) * 4 + r;
                        int col = nf * 16 + lr;
                        ldsC[row * 68 + (col ^ (((row >> 3) & 7) << 2))] =
                            acc[mf][nf][r];
                    }
        }
        __syncthreads();
#pragma unroll
        for (int q = 0; q < 2; ++q) {
            int idx = q * 256 + t;
            int ml = idx & 127;
            int oo = idx >> 7;
            int o  = nt * 8 + nh * 4 + oo;
            float bias = ub[o];
            int mg = m0 + ml;
            int b = mg >> 12, pix = mg & 4095;
            int h = pix >> 6, ww = pix & 63;
            long base = ((long)(b * 64 + o) * 256 + h * 4) * 256 + ww * 4;
#pragma unroll
            for (int i = 0; i < 4; ++i) {
                f32x4 cv = *(const f32x4*)&ldsC[ml * 68 +
                            ((oo * 16 + i * 4) ^ (((ml >> 3) & 7) << 2))];
                float4 xi = *(const float4*)&x[base + i * 256];
                float4 rr;
                rr.x = fmaxf(cv[0] + bias + xi.x, 0.f);
                rr.y = fmaxf(cv[1] + bias + xi.y, 0.f);
                rr.z = fmaxf(cv[2] + bias + xi.z, 0.f);
                rr.w = fmaxf(cv[3] + bias + xi.w, 0.f);
                *(float4*)&out[base + i * 256] = rr;
            }
        }
    }
}

// ---------------------------------------------------------------------------
extern "C" void kernel_launch(void* const* d_in, const int* in_sizes, int n_in,
                              void* d_out, int out_size, void* d_ws, size_t ws_size,
                              hipStream_t stream) {
    const float* x      = (const float*)d_in[0];
    const float* weight = (const float*)d_in[1];
    const float* pih_w  = (const float*)d_in[2];
    const float* pih_b  = (const float*)d_in[3];
    const float* up_w   = (const float*)d_in[4];
    const float* up_b   = (const float*)d_in[5];
    float* out = (float*)d_out;
    float* ws  = (float*)d_ws;

    // workspace layout (float offsets)
    u16*   xpc   = (u16*)ws;                   // 2,097,152 u16 NHWC bf16 pooled
    u16*   xpihb = (u16*)(ws + 2097152);       // 2,097,152 u16 conv out bf16 [c][n]
    u16*   Ab16  = (u16*)(ws + 3145728);       // 2,097,152 u16 GEMM A bf16
    float* G     = ws + 4194304;               // 32,768 f
    u16*   Lb16  = (u16*)(ws + 4227072);       // 32,768 u16 L bf16 [b][c][d]
    u16*   Wb    = (u16*)(ws + 4259840);       // 65,536 u16 convT B^T bf16
    u16*   WTb   = (u16*)(ws + 4325376);       // 16,777,216 u16 WT bf16 [N][K]
    u16*   Cp    = (u16*)(ws + 12713984);      // 8,388,608 u16: 4 bf16 partials
    u16*   Bpack = Cp + 2097152;               // conv weights (Cp dead until gemm)
    u16*   A2    = (u16*)ws;                   // out2T bf16 (xpc dead after diffuse)

    hipMemsetAsync(G, 0, 32768 * sizeof(float), stream);
    prep_k        <<<400, 256, 0, stream>>>(up_w, pih_w, Wb, Bpack);
    transWb_k     <<<dim3(64, 64), 256, 0, stream>>>(weight, WTb);
    maxpool_nhwc_k<<<512, 256, 0, stream>>>(x, xpc);
    conv_mfma_k   <<<512, 256, 0, stream>>>(xpc, Bpack, pih_b, xpihb);
    gram_mfma_k   <<<dim3(32, 8), 256, 0, stream>>>(xpihb, G);
    build_L_k     <<<8, 64, 0, stream>>>(G, Lb16);
    diffuse_mfma_k<<<dim3(32, 8), 256, 0, stream>>>(Lb16, xpc, Ab16);
    gemm_mfma_k   <<<512, 256, 0, stream>>>(Ab16, WTb, Cp);
    reduce4T_k    <<<dim3(64, 8), 256, 0, stream>>>(Cp, A2);
    convT_mfma_k  <<<dim3(256, 8), 256, 0, stream>>>(A2, Wb, up_b, x, out);
}

// Round 7
// 190.476 us; speedup vs baseline: 3.9205x; 1.0002x over previous
//
#include <hip/hip_runtime.h>

// Problem constants: b=8, c=64, hw=256, RATIO=4, HP=WP=64, N=4096.
#define NB 8
#define NC 64
#define HW 256
#define HP 64
#define NN 4096   // HP*WP

typedef unsigned short u16;
typedef unsigned int u32;
typedef __attribute__((ext_vector_type(8))) short s16x8;          // MFMA a/b frag (8 bf16)
typedef __attribute__((ext_vector_type(8))) unsigned short u16x8; // 16B bf16 vector
typedef __attribute__((ext_vector_type(4))) float f32x4;          // MFMA acc

__device__ __forceinline__ u16 f2bf(float f) {          // fp32 -> bf16 RNE
    unsigned u = __float_as_uint(f);
    return (u16)((u + 0x7fffu + ((u >> 16) & 1u)) >> 16);
}
__device__ __forceinline__ float bf2f(u16 v) {
    return __uint_as_float(((unsigned)v) << 16);
}

// global -> LDS direct, 16B per lane. LDS dest: wave-uniform base + lane*16.
#define GLOAD16(gsrc, ldst) \
    __builtin_amdgcn_global_load_lds((const __attribute__((address_space(1))) unsigned int*)(gsrc), \
                                     (__attribute__((address_space(3))) unsigned int*)(ldst), 16, 0, 0)

// ---------------------------------------------------------------------------
// K0: fused weight prep.
//  bid<256:  up_w [c][o][i][j] fp32 -> Wb bf16 [n=(o*4+i)*4+j][c]
//  bid>=256: pih_w [o][ci][3][3]  -> Bpack bf16 MFMA fragment order
__global__ __launch_bounds__(256) void prep_k(const float* __restrict__ uw,
                                              const float* __restrict__ pw,
                                              u16* __restrict__ Wb,
                                              u16* __restrict__ Bpack) {
    int bid = blockIdx.x;
    if (bid < 256) {
        int idx = bid * 256 + threadIdx.x;      // 0..65535
        int c = idx & 63;
        int n = idx >> 6;                       // (o,i,j)
        int o = n >> 4, i = (n >> 2) & 3, j = n & 3;
        Wb[idx] = f2bf(uw[((c * 64 + o) * 4 + i) * 4 + j]);
    } else {
        int idx = (bid - 256) * 256 + threadIdx.x;  // 0..36863
        if (idx >= 36864) return;
        int e = idx & 7, l = (idx >> 3) & 63, nf = (idx >> 9) & 3, s = idx >> 11;
        int ch = s & 1, kd = s >> 1;
        int dy = kd / 3, dx = kd % 3;
        int o  = nf * 16 + (l & 15);
        int ci = ch * 32 + (l >> 4) * 8 + e;
        Bpack[idx] = f2bf(pw[((o * 64 + ci) * 3 + dy) * 3 + dx]);
    }
}

// ---------------------------------------------------------------------------
// K0b: W fp32 [K][N] -> WT bf16 [N][K]  (tiled 64x64 transpose)
__global__ __launch_bounds__(256) void transWb_k(const float* __restrict__ W,
                                                 u16* __restrict__ WTb) {
    __shared__ float tile[64 * 65];
    int k0 = blockIdx.x * 64;
    int n0 = blockIdx.y * 64;
    int t = threadIdx.x;
#pragma unroll
    for (int i = 0; i < 4; ++i) {
        int idx = t + i * 256;                 // float4 id 0..1023
        int r  = idx >> 4;                     // k row
        int c4 = (idx & 15) * 4;               // n col
        float4 v = *(const float4*)&W[(long)(k0 + r) * 4096 + n0 + c4];
        tile[(c4 + 0) * 65 + r] = v.x;
        tile[(c4 + 1) * 65 + r] = v.y;
        tile[(c4 + 2) * 65 + r] = v.z;
        tile[(c4 + 3) * 65 + r] = v.w;
    }
    __syncthreads();
#pragma unroll
    for (int i = 0; i < 2; ++i) {
        int chunk = t + i * 256;               // 0..511
        int nr = chunk >> 3;
        int kc = (chunk & 7) * 8;
        u16x8 o;
#pragma unroll
        for (int j = 0; j < 8; ++j) o[j] = f2bf(tile[nr * 65 + kc + j]);
        *(u16x8*)&WTb[(long)(n0 + nr) * 4096 + k0 + kc] = o;
    }
}

// ---------------------------------------------------------------------------
// K1: maxpool 4x4 s4 + NCHW->NHWC + bf16.  x[8,64,256,256] -> xpc[b][y][x][c]
// Block = (b,y): reads x[b,:,4y..4y+4,:] (256 KB), writes one 8 KB xpc row-slab.
__global__ __launch_bounds__(256) void maxpool_nhwc_k(const float* __restrict__ x,
                                                      u16* __restrict__ xpc) {
    __shared__ u16 tile[64 * 66];               // [c][x] stride 66
    int bid = blockIdx.x;                       // 512
    int b = bid >> 6, y = bid & 63;
    int t = threadIdx.x;
    int c = t >> 2, q = t & 3;
    const float* p = x + ((long)(b * 64 + c) * 256 + y * 4) * 256 + q * 64;
#pragma unroll
    for (int i = 0; i < 16; ++i) {
        float m = -3.4e38f;
#pragma unroll
        for (int r = 0; r < 4; ++r) {
            float4 v = *(const float4*)(p + r * 256 + i * 4);
            m = fmaxf(m, fmaxf(fmaxf(v.x, v.y), fmaxf(v.z, v.w)));
        }
        tile[c * 66 + q * 16 + i] = f2bf(m);
    }
    __syncthreads();
    int xo = t >> 2, cp = t & 3;
    u16x8 o0, o1;
#pragma unroll
    for (int e = 0; e < 8; ++e) o0[e] = tile[(cp * 16 + e) * 66 + xo];
#pragma unroll
    for (int e = 0; e < 8; ++e) o1[e] = tile[(cp * 16 + 8 + e) * 66 + xo];
    u16* dst = xpc + ((long)(b * 4096 + y * 64 + xo)) * 64 + cp * 16;
    *(u16x8*)dst = o0;
    *(u16x8*)(dst + 8) = o1;
}

// ---------------------------------------------------------------------------
// K2: conv3x3 as implicit-GEMM MFMA -> xpihb bf16 [b*64+o][n=y*64+x]
__global__ __launch_bounds__(256) void conv_mfma_k(const u16* __restrict__ xpc,
                                                   const u16* __restrict__ Bpack,
                                                   const float* __restrict__ pb,
                                                   u16* __restrict__ xpihb) {
    __shared__ alignas(16) u16 ldsIn[3 * 66 * 64];   // 25344 B
    int bid = blockIdx.x;
    int b = bid >> 6, y = bid & 63;
    int t = threadIdx.x;
    int w = t >> 6, l = t & 63;
    int lr = l & 15, ksub = l >> 4;

    if (t < 48) {
        int r = t >> 4, q = t & 15;
        int off = r * 8448 + (q < 8 ? q * 16 : 8320 + (q - 8) * 16);
        *(u16x8*)((char*)ldsIn + off) = (u16x8){0, 0, 0, 0, 0, 0, 0, 0};
    }
#pragma unroll
    for (int i = 0; i < 6; ++i) {
        int r  = i >> 1;
        int ya = y - 1 + r;
        int wro = (i & 1) * 4096 + t * 16;      // within-row byte 0..8191
        int dst = r * 8448 + 128 + wro;
        if (ya >= 0 && ya < 64) {
            int xsl = 1 + (wro >> 7);
            int srcoff = (wro & ~127) | ((wro & 127) ^ ((xsl & 7) << 4));
            GLOAD16((const char*)xpc + (long)(b * 64 + ya) * 8192 + srcoff,
                    (char*)ldsIn + dst);
        } else {
            *(u16x8*)((char*)ldsIn + dst) = (u16x8){0, 0, 0, 0, 0, 0, 0, 0};
        }
    }
    __syncthreads();

    f32x4 acc[4];
#pragma unroll
    for (int mf = 0; mf < 4; ++mf) acc[mf] = (f32x4){0.f, 0.f, 0.f, 0.f};

#pragma unroll
    for (int kd = 0; kd < 9; ++kd) {
        int dy = kd / 3, dx = kd % 3;
#pragma unroll
        for (int ch = 0; ch < 2; ++ch) {
            int s = kd * 2 + ch;
            s16x8 bfrag = *(const s16x8*)(Bpack + ((s * 4 + w) * 64 + l) * 8);
#pragma unroll
            for (int mf = 0; mf < 4; ++mf) {
                int xsl  = mf * 16 + lr + dx;
                int coff = (ch * 64 + ksub * 16) ^ ((xsl & 7) << 4);
                s16x8 af = *(const s16x8*)((const char*)ldsIn +
                                           dy * 8448 + xsl * 128 + coff);
                acc[mf] = __builtin_amdgcn_mfma_f32_16x16x32_bf16(
                    af, bfrag, acc[mf], 0, 0, 0);
            }
        }
    }
    int o = w * 16 + lr;
    float bias = pb[o];
    u16* dst = xpihb + ((long)(b * 64 + o)) * 4096 + y * 64;
#pragma unroll
    for (int mf = 0; mf < 4; ++mf)
#pragma unroll
        for (int rp = 0; rp < 2; ++rp) {
            u16 lo = f2bf(fmaxf(acc[mf][rp * 2]     + bias, 0.f));
            u16 hi = f2bf(fmaxf(acc[mf][rp * 2 + 1] + bias, 0.f));
            *(u32*)&dst[mf * 16 + ksub * 4 + rp * 2] = (u32)lo | ((u32)hi << 16);
        }
}

// ---------------------------------------------------------------------------
// K3: Gram via MFMA.  G[b] += X Xᵀ over n-chunk of 128 (X = xpihb rows).
// Both MFMA operands come from the same staged [64c][128n] tile.
__global__ __launch_bounds__(256) void gram_mfma_k(const u16* __restrict__ xpihb,
                                                   float* __restrict__ G) {
    __shared__ alignas(16) u16 lds[64 * 128];    // 16 KB, 256 B rows
    int n0 = blockIdx.x * 128;
    int b  = blockIdx.y;
    int t = threadIdx.x;
    int w = t >> 6, l = t & 63;
    int lr = l & 15, ksub = l >> 4;
#pragma unroll
    for (int i = 0; i < 4; ++i) {
        int d = i * 4096 + t * 16;
        int row = d >> 8, off = d & 255;
        GLOAD16((const char*)xpihb + ((long)(b * 64 + row)) * 8192 + n0 * 2 +
                (off ^ ((row & 15) << 4)),
                (char*)lds + d);
    }
    __syncthreads();

    f32x4 acc[4];
#pragma unroll
    for (int mf = 0; mf < 4; ++mf) acc[mf] = (f32x4){0.f, 0.f, 0.f, 0.f};
#pragma unroll
    for (int kk = 0; kk < 4; ++kk) {
        int brow = w * 16 + lr;
        s16x8 bf = *(const s16x8*)((const char*)lds + brow * 256 +
                                   ((kk * 64 + ksub * 16) ^ ((brow & 15) << 4)));
#pragma unroll
        for (int mf = 0; mf < 4; ++mf) {
            int arow = mf * 16 + lr;
            s16x8 af = *(const s16x8*)((const char*)lds + arow * 256 +
                                       ((kk * 64 + ksub * 16) ^ ((arow & 15) << 4)));
            acc[mf] = __builtin_amdgcn_mfma_f32_16x16x32_bf16(af, bf, acc[mf], 0, 0, 0);
        }
    }
    float* Gb = G + b * 4096;
#pragma unroll
    for (int mf = 0; mf < 4; ++mf)
#pragma unroll
        for (int r = 0; r < 4; ++r)
            atomicAdd(&Gb[(mf * 16 + (l >> 4) * 4 + r) * 64 + w * 16 + lr],
                      acc[mf][r]);
}

// ---------------------------------------------------------------------------
// K4: build L -> Lb16 bf16 row-major [b][c][d]
__global__ void build_L_k(const float* __restrict__ G, u16* __restrict__ Lb16) {
    int b = blockIdx.x;
    int c = threadIdx.x;
    __shared__ float nrm[64], dvv[64];
    const float* Gb = G + b * 4096;
    float n = sqrtf(Gb[c * 64 + c]);
    n = fmaxf(n, 1e-12f);
    nrm[c] = n;
    __syncthreads();
    float rs = 0.f;
    for (int d = 0; d < 64; ++d) rs += Gb[c * 64 + d] / (n * nrm[d]);
    float dd = 1.0f / sqrtf(rs + 1e-8f);
    if (!(dd <= 3.0e38f)) dd = 0.0f;
    dvv[c] = dd;
    __syncthreads();
    for (int d = 0; d < 64; ++d) {
        float A = Gb[c * 64 + d] / (n * nrm[d]);
        float val = ((c == d) ? 1.0f : 0.0f) - dd * A * dvv[d];
        Lb16[(b * 64 + c) * 64 + d] = f2bf(val);
    }
}

// ---------------------------------------------------------------------------
// K5: diffuse via MFMA.  Ab16[b*64+c][n] = sum_d L[c][d] * xp[d][n].
// A-frags read Lb16 rows direct from global (L2-hot); B staged from xpc NHWC.
__global__ __launch_bounds__(256) void diffuse_mfma_k(const u16* __restrict__ Lb16,
                                                      const u16* __restrict__ xpc,
                                                      u16* __restrict__ Ab16) {
    __shared__ alignas(16) u16 lds[128 * 64];    // 16 KB, 128 B rows
    int n0 = blockIdx.x * 128;
    int b  = blockIdx.y;
    int t = threadIdx.x;
    int w = t >> 6, l = t & 63;
    int lr = l & 15, ksub = l >> 4;
#pragma unroll
    for (int i = 0; i < 4; ++i) {
        int d = i * 4096 + t * 16;
        int row = d >> 7, off = d & 127;
        GLOAD16((const char*)xpc + ((long)(b * 4096 + n0 + row)) * 128 +
                (off ^ ((row & 7) << 4)),
                (char*)lds + d);
    }
    __syncthreads();

    const u16* Lb = Lb16 + b * 4096;
    f32x4 acc[4][2];
#pragma unroll
    for (int mf = 0; mf < 4; ++mf)
#pragma unroll
        for (int nq = 0; nq < 2; ++nq) acc[mf][nq] = (f32x4){0.f, 0.f, 0.f, 0.f};

#pragma unroll
    for (int kk = 0; kk < 2; ++kk) {
        s16x8 bfr[2];
#pragma unroll
        for (int nq = 0; nq < 2; ++nq) {
            int brow = w * 32 + nq * 16 + lr;
            bfr[nq] = *(const s16x8*)((const char*)lds + brow * 128 +
                                      ((kk * 64 + ksub * 16) ^ ((brow & 7) << 4)));
        }
#pragma unroll
        for (int mf = 0; mf < 4; ++mf) {
            s16x8 af = *(const s16x8*)(Lb + (mf * 16 + lr) * 64 + kk * 32 + ksub * 8);
#pragma unroll
            for (int nq = 0; nq < 2; ++nq)
                acc[mf][nq] = __builtin_amdgcn_mfma_f32_16x16x32_bf16(
                    af, bfr[nq], acc[mf][nq], 0, 0, 0);
        }
    }
#pragma unroll
    for (int mf = 0; mf < 4; ++mf)
#pragma unroll
        for (int nq = 0; nq < 2; ++nq)
#pragma unroll
            for (int r = 0; r < 4; ++r)
                Ab16[((long)(b * 64 + mf * 16 + (l >> 4) * 4 + r)) * 4096 +
                     n0 + w * 32 + nq * 16 + lr] = f2bf(acc[mf][nq][r]);
}

// ---------------------------------------------------------------------------
// K6: bf16 MFMA GEMM, 2-phase double-buffered.
#define KSPLIT 4
#define KSLICE 1024
__global__ __launch_bounds__(256) void gemm_mfma_k(const u16* __restrict__ A,
                                                   const u16* __restrict__ WT,
                                                   u16* __restrict__ Cp) {
    __shared__ alignas(16) u16 ldsA[2][8192];   // 2 x 16 KB
    __shared__ alignas(16) u16 ldsB[2][8192];
    int bid = blockIdx.x;                    // 512 blocks
    int swz = (bid & 7) * 64 + (bid >> 3);   // XCD-chunked (512 % 8 == 0)
    int m0 = (swz & 3) * 128;
    int n0 = ((swz >> 2) & 31) * 128;
    int z  = swz >> 7;
    int t = threadIdx.x;
    int w = t >> 6, l = t & 63;
    int wr = w >> 1, wc = w & 1;
    int lr = l & 15;
    int lk = (l >> 4) << 4;

    f32x4 acc[4][4];
#pragma unroll
    for (int mf = 0; mf < 4; ++mf)
#pragma unroll
        for (int nf = 0; nf < 4; ++nf) acc[mf][nf] = (f32x4){0.f, 0.f, 0.f, 0.f};

    const char* Ab = (const char*)(A  + (long)m0 * 4096 + z * KSLICE);
    const char* Bb = (const char*)(WT + (long)n0 * 4096 + z * KSLICE);

    auto stage = [&](int buf, int k0) {
#pragma unroll
        for (int i = 0; i < 4; ++i) {
            int d   = i * 4096 + t * 16;
            int row = d >> 7;
            int off = d & 127;
            int sk  = off ^ ((row & 7) << 4);
            GLOAD16(Ab + (long)row * 8192 + k0 * 2 + sk, (char*)ldsA[buf] + d);
            GLOAD16(Bb + (long)row * 8192 + k0 * 2 + sk, (char*)ldsB[buf] + d);
        }
    };

    stage(0, 0);
    __syncthreads();
    int cur = 0;
    for (int k0 = 0; k0 < KSLICE; k0 += 64) {
        if (k0 + 64 < KSLICE) stage(cur ^ 1, k0 + 64);
#pragma unroll
        for (int kk = 0; kk < 2; ++kk) {
            s16x8 af[4], bf[4];
#pragma unroll
            for (int f = 0; f < 4; ++f) {
                int ar = wr * 64 + f * 16 + lr;
                af[f] = *(const s16x8*)((const char*)ldsA[cur] + ar * 128 +
                                        ((kk * 64 + lk) ^ ((ar & 7) << 4)));
                int br = wc * 64 + f * 16 + lr;
                bf[f] = *(const s16x8*)((const char*)ldsB[cur] + br * 128 +
                                        ((kk * 64 + lk) ^ ((br & 7) << 4)));
            }
#pragma unroll
            for (int mf = 0; mf < 4; ++mf)
#pragma unroll
                for (int nf = 0; nf < 4; ++nf)
                    acc[mf][nf] = __builtin_amdgcn_mfma_f32_16x16x32_bf16(
                        af[mf], bf[nf], acc[mf][nf], 0, 0, 0);
        }
        __syncthreads();
        cur ^= 1;
    }
    u16* Cz = Cp + (long)z * 2097152;
#pragma unroll
    for (int mf = 0; mf < 4; ++mf)
#pragma unroll
        for (int nf = 0; nf < 4; ++nf)
#pragma unroll
            for (int r = 0; r < 4; ++r) {
                int row = m0 + wr * 64 + mf * 16 + (l >> 4) * 4 + r;
                int col = n0 + wc * 64 + nf * 16 + lr;
                Cz[(long)row * 4096 + col] = f2bf(acc[mf][nf][r]);
            }
}

// ---------------------------------------------------------------------------
// K6b: A2[b*4096+n][c] (bf16) = sum_z Cp[z][b*64+c][n]   (reduce + transpose)
__global__ __launch_bounds__(256) void reduce4T_k(const u16* __restrict__ Cp,
                                                  u16* __restrict__ A2) {
    __shared__ float xs[64 * 65];
    int n0 = blockIdx.x * 64;
    int b  = blockIdx.y;
    int t = threadIdx.x;
    int c = t >> 2, seg = t & 3;
    float s[16];
#pragma unroll
    for (int k = 0; k < 16; ++k) s[k] = 0.f;
#pragma unroll
    for (int z = 0; z < KSPLIT; ++z) {
        const u16* p = Cp + ((long)z * 512 + b * 64 + c) * 4096 + n0 + seg * 16;
        u16x8 v0 = *(const u16x8*)p;
        u16x8 v1 = *(const u16x8*)(p + 8);
#pragma unroll
        for (int k = 0; k < 8; ++k) {
            s[k]     += bf2f(v0[k]);
            s[8 + k] += bf2f(v1[k]);
        }
    }
#pragma unroll
    for (int k = 0; k < 16; ++k) xs[c * 65 + seg * 16 + k] = s[k];
    __syncthreads();
    int n = t >> 2, q = t & 3;
    u16x8 o0, o1;
#pragma unroll
    for (int k = 0; k < 8; ++k) o0[k] = f2bf(xs[(q * 16 + k) * 65 + n]);
#pragma unroll
    for (int k = 0; k < 8; ++k) o1[k] = f2bf(xs[(q * 16 + 8 + k) * 65 + n]);
    u16* dst = A2 + ((long)b * 4096 + n0 + n) * 64 + q * 16;
    *(u16x8*)dst = o0;
    *(u16x8*)(dst + 8) = o1;
}

// ---------------------------------------------------------------------------
// K7: convT as MFMA GEMM with LDS-bounced, fully-coalesced epilogue.
__global__ __launch_bounds__(256) void convT_mfma_k(const u16* __restrict__ A2,
                                                    const u16* __restrict__ Wb,
                                                    const float* __restrict__ ub,
                                                    const float* __restrict__ x,
                                                    float* __restrict__ out) {
    __shared__ alignas(16) char smem[34816];     // staging 32KB | C-bounce 128x68 f32
    u16*   ldsA = (u16*)smem;
    u16*   ldsB = (u16*)(smem + 16384);
    float* ldsC = (float*)smem;
    int mt = blockIdx.x;
    int nt = blockIdx.y;
    int m0 = mt * 128;
    int n0 = nt * 128;
    int t = threadIdx.x;
    int w = t >> 6, l = t & 63;
    int wr = w >> 1, wc = w & 1;
    int lr = l & 15;
    int lkb = (l >> 4) << 4;

    const char* Ab = (const char*)(A2 + (long)m0 * 64);
    const char* Bb = (const char*)(Wb + (long)n0 * 64);
#pragma unroll
    for (int i = 0; i < 4; ++i) {
        int d = i * 4096 + t * 16;
        int srcoff = (d & ~127) | ((d & 127) ^ (((d >> 7) & 7) << 4));
        GLOAD16(Ab + srcoff, (char*)ldsA + d);
        GLOAD16(Bb + srcoff, (char*)ldsB + d);
    }
    __syncthreads();

    f32x4 acc[4][4];
#pragma unroll
    for (int mf = 0; mf < 4; ++mf)
#pragma unroll
        for (int nf = 0; nf < 4; ++nf) acc[mf][nf] = (f32x4){0.f, 0.f, 0.f, 0.f};

#pragma unroll
    for (int kk = 0; kk < 2; ++kk) {
        s16x8 af[4], bfg[4];
#pragma unroll
        for (int f = 0; f < 4; ++f) {
            int ar = wr * 64 + f * 16 + lr;
            af[f] = *(const s16x8*)((const char*)ldsA + ar * 128 +
                                    ((kk * 64 + lkb) ^ ((ar & 7) << 4)));
            int br = wc * 64 + f * 16 + lr;
            bfg[f] = *(const s16x8*)((const char*)ldsB + br * 128 +
                                     ((kk * 64 + lkb) ^ ((br & 7) << 4)));
        }
#pragma unroll
        for (int mf = 0; mf < 4; ++mf)
#pragma unroll
            for (int nf = 0; nf < 4; ++nf)
                acc[mf][nf] = __builtin_amdgcn_mfma_f32_16x16x32_bf16(
                    af[mf], bfg[nf], acc[mf][nf], 0, 0, 0);
    }
    __syncthreads();

#pragma unroll
    for (int nh = 0; nh < 2; ++nh) {
        if (nh) __syncthreads();
        if (wc == nh) {
#pragma unroll
            for (int mf = 0; mf < 4; ++mf)
#pragma unroll
                for (int nf = 0; nf < 4; ++nf)
#pragma unroll
                    for (int r = 0; r < 4; ++r) {
                        int row = wr * 64 + mf * 16 + (l >> 4) * 4 + r;
                        int col = nf * 16 + lr;
                        ldsC[row * 68 + (col ^ (((row >> 3) & 7) << 2))] =
                            acc[mf][nf][r];
                    }
        }
        __syncthreads();
#pragma unroll
        for (int q = 0; q < 2; ++q) {
            int idx = q * 256 + t;
            int ml = idx & 127;
            int oo = idx >> 7;
            int o  = nt * 8 + nh * 4 + oo;
            float bias = ub[o];
            int mg = m0 + ml;
            int b = mg >> 12, pix = mg & 4095;
            int h = pix >> 6, ww = pix & 63;
            long base = ((long)(b * 64 + o) * 256 + h * 4) * 256 + ww * 4;
#pragma unroll
            for (int i = 0; i < 4; ++i) {
                f32x4 cv = *(const f32x4*)&ldsC[ml * 68 +
                            ((oo * 16 + i * 4) ^ (((ml >> 3) & 7) << 2))];
                float4 xi = *(const float4*)&x[base + i * 256];
                float4 rr;
                rr.x = fmaxf(cv[0] + bias + xi.x, 0.f);
                rr.y = fmaxf(cv[1] + bias + xi.y, 0.f);
                rr.z = fmaxf(cv[2] + bias + xi.z, 0.f);
                rr.w = fmaxf(cv[3] + bias + xi.w, 0.f);
                *(float4*)&out[base + i * 256] = rr;
            }
        }
    }
}

// ---------------------------------------------------------------------------
extern "C" void kernel_launch(void* const* d_in, const int* in_sizes, int n_in,
                              void* d_out, int out_size, void* d_ws, size_t ws_size,
                              hipStream_t stream) {
    const float* x      = (const float*)d_in[0];
    const float* weight = (const float*)d_in[1];
    const float* pih_w  = (const float*)d_in[2];
    const float* pih_b  = (const float*)d_in[3];
    const float* up_w   = (const float*)d_in[4];
    const float* up_b   = (const float*)d_in[5];
    float* out = (float*)d_out;
    float* ws  = (float*)d_ws;

    // workspace layout (float offsets)
    u16*   xpc   = (u16*)ws;                   // 2,097,152 u16 NHWC bf16 pooled
    u16*   xpihb = (u16*)(ws + 2097152);       // 2,097,152 u16 conv out bf16 [c][n]
    u16*   Ab16  = (u16*)(ws + 3145728);       // 2,097,152 u16 GEMM A bf16
    float* G     = ws + 4194304;               // 32,768 f
    u16*   Lb16  = (u16*)(ws + 4227072);       // 32,768 u16 L bf16 [b][c][d]
    u16*   Wb    = (u16*)(ws + 4259840);       // 65,536 u16 convT B^T bf16
    u16*   WTb   = (u16*)(ws + 4325376);       // 16,777,216 u16 WT bf16 [N][K]
    u16*   Cp    = (u16*)(ws + 12713984);      // 8,388,608 u16: 4 bf16 partials
    u16*   Bpack = Cp + 2097152;               // conv weights (Cp dead until gemm)
    u16*   A2    = (u16*)ws;                   // out2T bf16 (xpc dead after diffuse)

    hipMemsetAsync(G, 0, 32768 * sizeof(float), stream);
    prep_k        <<<400, 256, 0, stream>>>(up_w, pih_w, Wb, Bpack);
    transWb_k     <<<dim3(64, 64), 256, 0, stream>>>(weight, WTb);
    maxpool_nhwc_k<<<512, 256, 0, stream>>>(x, xpc);
    conv_mfma_k   <<<512, 256, 0, stream>>>(xpc, Bpack, pih_b, xpihb);
    gram_mfma_k   <<<dim3(32, 8), 256, 0, stream>>>(xpihb, G);
    build_L_k     <<<8, 64, 0, stream>>>(G, Lb16);
    diffuse_mfma_k<<<dim3(32, 8), 256, 0, stream>>>(Lb16, xpc, Ab16);
    gemm_mfma_k   <<<512, 256, 0, stream>>>(Ab16, WTb, Cp);
    reduce4T_k    <<<dim3(64, 8), 256, 0, stream>>>(Cp, A2);
    convT_mfma_k  <<<dim3(256, 8), 256, 0, stream>>>(A2, Wb, up_b, x, out);
}

// Round 8
// 190.021 us; speedup vs baseline: 3.9299x; 1.0024x over previous
//
#include <hip/hip_runtime.h>

// Problem constants: b=8, c=64, hw=256, RATIO=4, HP=WP=64, N=4096.
#define NB 8
#define NC 64
#define HW 256
#define HP 64
#define NN 4096   // HP*WP

typedef unsigned short u16;
typedef unsigned int u32;
typedef __attribute__((ext_vector_type(8))) short s16x8;          // MFMA a/b frag (8 bf16)
typedef __attribute__((ext_vector_type(8))) unsigned short u16x8; // 16B bf16 vector
typedef __attribute__((ext_vector_type(4))) float f32x4;          // MFMA acc

__device__ __forceinline__ u16 f2bf(float f) {          // fp32 -> bf16 RNE
    unsigned u = __float_as_uint(f);
    return (u16)((u + 0x7fffu + ((u >> 16) & 1u)) >> 16);
}
__device__ __forceinline__ float bf2f(u16 v) {
    return __uint_as_float(((unsigned)v) << 16);
}

// global -> LDS direct, 16B per lane. LDS dest: wave-uniform base + lane*16.
#define GLOAD16(gsrc, ldst) \
    __builtin_amdgcn_global_load_lds((const __attribute__((address_space(1))) unsigned int*)(gsrc), \
                                     (__attribute__((address_space(3))) unsigned int*)(ldst), 16, 0, 0)

// ---------------------------------------------------------------------------
// K0: fused weight prep.
//  bid<256:  up_w [c][o][i][j] fp32 -> Wb bf16 [n=(o*4+i)*4+j][c]
//  bid>=256: pih_w [o][ci][3][3]  -> Bpack bf16 MFMA fragment order
__global__ __launch_bounds__(256) void prep_k(const float* __restrict__ uw,
                                              const float* __restrict__ pw,
                                              u16* __restrict__ Wb,
                                              u16* __restrict__ Bpack) {
    int bid = blockIdx.x;
    if (bid < 256) {
        int idx = bid * 256 + threadIdx.x;      // 0..65535
        int c = idx & 63;
        int n = idx >> 6;                       // (o,i,j)
        int o = n >> 4, i = (n >> 2) & 3, j = n & 3;
        Wb[idx] = f2bf(uw[((c * 64 + o) * 4 + i) * 4 + j]);
    } else {
        int idx = (bid - 256) * 256 + threadIdx.x;  // 0..36863
        if (idx >= 36864) return;
        int e = idx & 7, l = (idx >> 3) & 63, nf = (idx >> 9) & 3, s = idx >> 11;
        int ch = s & 1, kd = s >> 1;
        int dy = kd / 3, dx = kd % 3;
        int o  = nf * 16 + (l & 15);
        int ci = ch * 32 + (l >> 4) * 8 + e;
        Bpack[idx] = f2bf(pw[((o * 64 + ci) * 3 + dy) * 3 + dx]);
    }
}

// ---------------------------------------------------------------------------
// K0b: W fp32 [K][N] -> WT bf16 [N][K]  (tiled 64x64 transpose)
__global__ __launch_bounds__(256) void transWb_k(const float* __restrict__ W,
                                                 u16* __restrict__ WTb) {
    __shared__ float tile[64 * 65];
    int k0 = blockIdx.x * 64;
    int n0 = blockIdx.y * 64;
    int t = threadIdx.x;
#pragma unroll
    for (int i = 0; i < 4; ++i) {
        int idx = t + i * 256;                 // float4 id 0..1023
        int r  = idx >> 4;                     // k row
        int c4 = (idx & 15) * 4;               // n col
        float4 v = *(const float4*)&W[(long)(k0 + r) * 4096 + n0 + c4];
        tile[(c4 + 0) * 65 + r] = v.x;
        tile[(c4 + 1) * 65 + r] = v.y;
        tile[(c4 + 2) * 65 + r] = v.z;
        tile[(c4 + 3) * 65 + r] = v.w;
    }
    __syncthreads();
#pragma unroll
    for (int i = 0; i < 2; ++i) {
        int chunk = t + i * 256;               // 0..511
        int nr = chunk >> 3;
        int kc = (chunk & 7) * 8;
        u16x8 o;
#pragma unroll
        for (int j = 0; j < 8; ++j) o[j] = f2bf(tile[nr * 65 + kc + j]);
        *(u16x8*)&WTb[(long)(n0 + nr) * 4096 + k0 + kc] = o;
    }
}

// ---------------------------------------------------------------------------
// K1: maxpool 4x4 s4 + NCHW->NHWC + bf16.  x[8,64,256,256] -> xpc[b][y][x][c]
// Block = (b,y): reads x[b,:,4y..4y+4,:] (256 KB), writes one 8 KB xpc row-slab.
__global__ __launch_bounds__(256) void maxpool_nhwc_k(const float* __restrict__ x,
                                                      u16* __restrict__ xpc) {
    __shared__ u16 tile[64 * 66];               // [c][x] stride 66
    int bid = blockIdx.x;                       // 512
    int b = bid >> 6, y = bid & 63;
    int t = threadIdx.x;
    int c = t >> 2, q = t & 3;
    const float* p = x + ((long)(b * 64 + c) * 256 + y * 4) * 256 + q * 64;
#pragma unroll
    for (int i = 0; i < 16; ++i) {
        float m = -3.4e38f;
#pragma unroll
        for (int r = 0; r < 4; ++r) {
            float4 v = *(const float4*)(p + r * 256 + i * 4);
            m = fmaxf(m, fmaxf(fmaxf(v.x, v.y), fmaxf(v.z, v.w)));
        }
        tile[c * 66 + q * 16 + i] = f2bf(m);
    }
    __syncthreads();
    int xo = t >> 2, cp = t & 3;
    u16x8 o0, o1;
#pragma unroll
    for (int e = 0; e < 8; ++e) o0[e] = tile[(cp * 16 + e) * 66 + xo];
#pragma unroll
    for (int e = 0; e < 8; ++e) o1[e] = tile[(cp * 16 + 8 + e) * 66 + xo];
    u16* dst = xpc + ((long)(b * 4096 + y * 64 + xo)) * 64 + cp * 16;
    *(u16x8*)dst = o0;
    *(u16x8*)(dst + 8) = o1;
}

// ---------------------------------------------------------------------------
// K2: conv3x3 as implicit-GEMM MFMA -> xpihb bf16 [b*64+o][n=y*64+x]
__global__ __launch_bounds__(256) void conv_mfma_k(const u16* __restrict__ xpc,
                                                   const u16* __restrict__ Bpack,
                                                   const float* __restrict__ pb,
                                                   u16* __restrict__ xpihb) {
    __shared__ alignas(16) u16 ldsIn[3 * 66 * 64];   // 25344 B
    int bid = blockIdx.x;
    int b = bid >> 6, y = bid & 63;
    int t = threadIdx.x;
    int w = t >> 6, l = t & 63;
    int lr = l & 15, ksub = l >> 4;

    if (t < 48) {
        int r = t >> 4, q = t & 15;
        int off = r * 8448 + (q < 8 ? q * 16 : 8320 + (q - 8) * 16);
        *(u16x8*)((char*)ldsIn + off) = (u16x8){0, 0, 0, 0, 0, 0, 0, 0};
    }
#pragma unroll
    for (int i = 0; i < 6; ++i) {
        int r  = i >> 1;
        int ya = y - 1 + r;
        int wro = (i & 1) * 4096 + t * 16;      // within-row byte 0..8191
        int dst = r * 8448 + 128 + wro;
        if (ya >= 0 && ya < 64) {
            int xsl = 1 + (wro >> 7);
            int srcoff = (wro & ~127) | ((wro & 127) ^ ((xsl & 7) << 4));
            GLOAD16((const char*)xpc + (long)(b * 64 + ya) * 8192 + srcoff,
                    (char*)ldsIn + dst);
        } else {
            *(u16x8*)((char*)ldsIn + dst) = (u16x8){0, 0, 0, 0, 0, 0, 0, 0};
        }
    }
    __syncthreads();

    f32x4 acc[4];
#pragma unroll
    for (int mf = 0; mf < 4; ++mf) acc[mf] = (f32x4){0.f, 0.f, 0.f, 0.f};

#pragma unroll
    for (int kd = 0; kd < 9; ++kd) {
        int dy = kd / 3, dx = kd % 3;
#pragma unroll
        for (int ch = 0; ch < 2; ++ch) {
            int s = kd * 2 + ch;
            s16x8 bfrag = *(const s16x8*)(Bpack + ((s * 4 + w) * 64 + l) * 8);
#pragma unroll
            for (int mf = 0; mf < 4; ++mf) {
                int xsl  = mf * 16 + lr + dx;
                int coff = (ch * 64 + ksub * 16) ^ ((xsl & 7) << 4);
                s16x8 af = *(const s16x8*)((const char*)ldsIn +
                                           dy * 8448 + xsl * 128 + coff);
                acc[mf] = __builtin_amdgcn_mfma_f32_16x16x32_bf16(
                    af, bfrag, acc[mf], 0, 0, 0);
            }
        }
    }
    int o = w * 16 + lr;
    float bias = pb[o];
    u16* dst = xpihb + ((long)(b * 64 + o)) * 4096 + y * 64;
#pragma unroll
    for (int mf = 0; mf < 4; ++mf)
#pragma unroll
        for (int rp = 0; rp < 2; ++rp) {
            u16 lo = f2bf(fmaxf(acc[mf][rp * 2]     + bias, 0.f));
            u16 hi = f2bf(fmaxf(acc[mf][rp * 2 + 1] + bias, 0.f));
            *(u32*)&dst[mf * 16 + ksub * 4 + rp * 2] = (u32)lo | ((u32)hi << 16);
        }
}

// ---------------------------------------------------------------------------
// K3: Gram via MFMA.  G[b] += X Xᵀ over n-chunk of 128 (X = xpihb rows).
// Both MFMA operands come from the same staged [64c][128n] tile.
__global__ __launch_bounds__(256) void gram_mfma_k(const u16* __restrict__ xpihb,
                                                   float* __restrict__ G) {
    __shared__ alignas(16) u16 lds[64 * 128];    // 16 KB, 256 B rows
    int n0 = blockIdx.x * 128;
    int b  = blockIdx.y;
    int t = threadIdx.x;
    int w = t >> 6, l = t & 63;
    int lr = l & 15, ksub = l >> 4;
#pragma unroll
    for (int i = 0; i < 4; ++i) {
        int d = i * 4096 + t * 16;
        int row = d >> 8, off = d & 255;
        GLOAD16((const char*)xpihb + ((long)(b * 64 + row)) * 8192 + n0 * 2 +
                (off ^ ((row & 15) << 4)),
                (char*)lds + d);
    }
    __syncthreads();

    f32x4 acc[4];
#pragma unroll
    for (int mf = 0; mf < 4; ++mf) acc[mf] = (f32x4){0.f, 0.f, 0.f, 0.f};
#pragma unroll
    for (int kk = 0; kk < 4; ++kk) {
        int brow = w * 16 + lr;
        s16x8 bf = *(const s16x8*)((const char*)lds + brow * 256 +
                                   ((kk * 64 + ksub * 16) ^ ((brow & 15) << 4)));
#pragma unroll
        for (int mf = 0; mf < 4; ++mf) {
            int arow = mf * 16 + lr;
            s16x8 af = *(const s16x8*)((const char*)lds + arow * 256 +
                                       ((kk * 64 + ksub * 16) ^ ((arow & 15) << 4)));
            acc[mf] = __builtin_amdgcn_mfma_f32_16x16x32_bf16(af, bf, acc[mf], 0, 0, 0);
        }
    }
    float* Gb = G + b * 4096;
#pragma unroll
    for (int mf = 0; mf < 4; ++mf)
#pragma unroll
        for (int r = 0; r < 4; ++r)
            atomicAdd(&Gb[(mf * 16 + (l >> 4) * 4 + r) * 64 + w * 16 + lr],
                      acc[mf][r]);
}

// ---------------------------------------------------------------------------
// K4: build L -> Lb16 bf16 row-major [b][c][d]
__global__ void build_L_k(const float* __restrict__ G, u16* __restrict__ Lb16) {
    int b = blockIdx.x;
    int c = threadIdx.x;
    __shared__ float nrm[64], dvv[64];
    const float* Gb = G + b * 4096;
    float n = sqrtf(Gb[c * 64 + c]);
    n = fmaxf(n, 1e-12f);
    nrm[c] = n;
    __syncthreads();
    float rs = 0.f;
    for (int d = 0; d < 64; ++d) rs += Gb[c * 64 + d] / (n * nrm[d]);
    float dd = 1.0f / sqrtf(rs + 1e-8f);
    if (!(dd <= 3.0e38f)) dd = 0.0f;
    dvv[c] = dd;
    __syncthreads();
    for (int d = 0; d < 64; ++d) {
        float A = Gb[c * 64 + d] / (n * nrm[d]);
        float val = ((c == d) ? 1.0f : 0.0f) - dd * A * dvv[d];
        Lb16[(b * 64 + c) * 64 + d] = f2bf(val);
    }
}

// ---------------------------------------------------------------------------
// K5: diffuse via MFMA.  Ab16[b*64+c][n] = sum_d L[c][d] * xp[d][n].
// A-frags read Lb16 rows direct from global (L2-hot); B staged from xpc NHWC.
__global__ __launch_bounds__(256) void diffuse_mfma_k(const u16* __restrict__ Lb16,
                                                      const u16* __restrict__ xpc,
                                                      u16* __restrict__ Ab16) {
    __shared__ alignas(16) u16 lds[128 * 64];    // 16 KB, 128 B rows
    int n0 = blockIdx.x * 128;
    int b  = blockIdx.y;
    int t = threadIdx.x;
    int w = t >> 6, l = t & 63;
    int lr = l & 15, ksub = l >> 4;
#pragma unroll
    for (int i = 0; i < 4; ++i) {
        int d = i * 4096 + t * 16;
        int row = d >> 7, off = d & 127;
        GLOAD16((const char*)xpc + ((long)(b * 4096 + n0 + row)) * 128 +
                (off ^ ((row & 7) << 4)),
                (char*)lds + d);
    }
    __syncthreads();

    const u16* Lb = Lb16 + b * 4096;
    f32x4 acc[4][2];
#pragma unroll
    for (int mf = 0; mf < 4; ++mf)
#pragma unroll
        for (int nq = 0; nq < 2; ++nq) acc[mf][nq] = (f32x4){0.f, 0.f, 0.f, 0.f};

#pragma unroll
    for (int kk = 0; kk < 2; ++kk) {
        s16x8 bfr[2];
#pragma unroll
        for (int nq = 0; nq < 2; ++nq) {
            int brow = w * 32 + nq * 16 + lr;
            bfr[nq] = *(const s16x8*)((const char*)lds + brow * 128 +
                                      ((kk * 64 + ksub * 16) ^ ((brow & 7) << 4)));
        }
#pragma unroll
        for (int mf = 0; mf < 4; ++mf) {
            s16x8 af = *(const s16x8*)(Lb + (mf * 16 + lr) * 64 + kk * 32 + ksub * 8);
#pragma unroll
            for (int nq = 0; nq < 2; ++nq)
                acc[mf][nq] = __builtin_amdgcn_mfma_f32_16x16x32_bf16(
                    af, bfr[nq], acc[mf][nq], 0, 0, 0);
        }
    }
#pragma unroll
    for (int mf = 0; mf < 4; ++mf)
#pragma unroll
        for (int nq = 0; nq < 2; ++nq)
#pragma unroll
            for (int r = 0; r < 4; ++r)
                Ab16[((long)(b * 64 + mf * 16 + (l >> 4) * 4 + r)) * 4096 +
                     n0 + w * 32 + nq * 16 + lr] = f2bf(acc[mf][nq][r]);
}

// ---------------------------------------------------------------------------
// K6: bf16 MFMA GEMM, 2-phase double-buffered.
#define KSPLIT 4
#define KSLICE 1024
__global__ __launch_bounds__(256) void gemm_mfma_k(const u16* __restrict__ A,
                                                   const u16* __restrict__ WT,
                                                   u16* __restrict__ Cp) {
    __shared__ alignas(16) u16 ldsA[2][8192];   // 2 x 16 KB
    __shared__ alignas(16) u16 ldsB[2][8192];
    int bid = blockIdx.x;                    // 512 blocks
    int swz = (bid & 7) * 64 + (bid >> 3);   // XCD-chunked (512 % 8 == 0)
    int m0 = (swz & 3) * 128;
    int n0 = ((swz >> 2) & 31) * 128;
    int z  = swz >> 7;
    int t = threadIdx.x;
    int w = t >> 6, l = t & 63;
    int wr = w >> 1, wc = w & 1;
    int lr = l & 15;
    int lk = (l >> 4) << 4;

    f32x4 acc[4][4];
#pragma unroll
    for (int mf = 0; mf < 4; ++mf)
#pragma unroll
        for (int nf = 0; nf < 4; ++nf) acc[mf][nf] = (f32x4){0.f, 0.f, 0.f, 0.f};

    const char* Ab = (const char*)(A  + (long)m0 * 4096 + z * KSLICE);
    const char* Bb = (const char*)(WT + (long)n0 * 4096 + z * KSLICE);

    auto stage = [&](int buf, int k0) {
#pragma unroll
        for (int i = 0; i < 4; ++i) {
            int d   = i * 4096 + t * 16;
            int row = d >> 7;
            int off = d & 127;
            int sk  = off ^ ((row & 7) << 4);
            GLOAD16(Ab + (long)row * 8192 + k0 * 2 + sk, (char*)ldsA[buf] + d);
            GLOAD16(Bb + (long)row * 8192 + k0 * 2 + sk, (char*)ldsB[buf] + d);
        }
    };

    stage(0, 0);
    __syncthreads();
    int cur = 0;
    for (int k0 = 0; k0 < KSLICE; k0 += 64) {
        if (k0 + 64 < KSLICE) stage(cur ^ 1, k0 + 64);
#pragma unroll
        for (int kk = 0; kk < 2; ++kk) {
            s16x8 af[4], bf[4];
#pragma unroll
            for (int f = 0; f < 4; ++f) {
                int ar = wr * 64 + f * 16 + lr;
                af[f] = *(const s16x8*)((const char*)ldsA[cur] + ar * 128 +
                                        ((kk * 64 + lk) ^ ((ar & 7) << 4)));
                int br = wc * 64 + f * 16 + lr;
                bf[f] = *(const s16x8*)((const char*)ldsB[cur] + br * 128 +
                                        ((kk * 64 + lk) ^ ((br & 7) << 4)));
            }
#pragma unroll
            for (int mf = 0; mf < 4; ++mf)
#pragma unroll
                for (int nf = 0; nf < 4; ++nf)
                    acc[mf][nf] = __builtin_amdgcn_mfma_f32_16x16x32_bf16(
                        af[mf], bf[nf], acc[mf][nf], 0, 0, 0);
        }
        __syncthreads();
        cur ^= 1;
    }
    u16* Cz = Cp + (long)z * 2097152;
#pragma unroll
    for (int mf = 0; mf < 4; ++mf)
#pragma unroll
        for (int nf = 0; nf < 4; ++nf)
#pragma unroll
            for (int r = 0; r < 4; ++r) {
                int row = m0 + wr * 64 + mf * 16 + (l >> 4) * 4 + r;
                int col = n0 + wc * 64 + nf * 16 + lr;
                Cz[(long)row * 4096 + col] = f2bf(acc[mf][nf][r]);
            }
}

// ---------------------------------------------------------------------------
// K6b: A2[b*4096+n][c] (bf16) = sum_z Cp[z][b*64+c][n]   (reduce + transpose)
__global__ __launch_bounds__(256) void reduce4T_k(const u16* __restrict__ Cp,
                                                  u16* __restrict__ A2) {
    __shared__ float xs[64 * 65];
    int n0 = blockIdx.x * 64;
    int b  = blockIdx.y;
    int t = threadIdx.x;
    int c = t >> 2, seg = t & 3;
    float s[16];
#pragma unroll
    for (int k = 0; k < 16; ++k) s[k] = 0.f;
#pragma unroll
    for (int z = 0; z < KSPLIT; ++z) {
        const u16* p = Cp + ((long)z * 512 + b * 64 + c) * 4096 + n0 + seg * 16;
        u16x8 v0 = *(const u16x8*)p;
        u16x8 v1 = *(const u16x8*)(p + 8);
#pragma unroll
        for (int k = 0; k < 8; ++k) {
            s[k]     += bf2f(v0[k]);
            s[8 + k] += bf2f(v1[k]);
        }
    }
#pragma unroll
    for (int k = 0; k < 16; ++k) xs[c * 65 + seg * 16 + k] = s[k];
    __syncthreads();
    int n = t >> 2, q = t & 3;
    u16x8 o0, o1;
#pragma unroll
    for (int k = 0; k < 8; ++k) o0[k] = f2bf(xs[(q * 16 + k) * 65 + n]);
#pragma unroll
    for (int k = 0; k < 8; ++k) o1[k] = f2bf(xs[(q * 16 + 8 + k) * 65 + n]);
    u16* dst = A2 + ((long)b * 4096 + n0 + n) * 64 + q * 16;
    *(u16x8*)dst = o0;
    *(u16x8*)(dst + 8) = o1;
}

// ---------------------------------------------------------------------------
// K7: convT as MFMA GEMM with LDS-bounced, fully-coalesced epilogue.
__global__ __launch_bounds__(256) void convT_mfma_k(const u16* __restrict__ A2,
                                                    const u16* __restrict__ Wb,
                                                    const float* __restrict__ ub,
                                                    const float* __restrict__ x,
                                                    float* __restrict__ out) {
    __shared__ alignas(16) char smem[34816];     // staging 32KB | C-bounce 128x68 f32
    u16*   ldsA = (u16*)smem;
    u16*   ldsB = (u16*)(smem + 16384);
    float* ldsC = (float*)smem;
    int mt = blockIdx.x;
    int nt = blockIdx.y;
    int m0 = mt * 128;
    int n0 = nt * 128;
    int t = threadIdx.x;
    int w = t >> 6, l = t & 63;
    int wr = w >> 1, wc = w & 1;
    int lr = l & 15;
    int lkb = (l >> 4) << 4;

    const char* Ab = (const char*)(A2 + (long)m0 * 64);
    const char* Bb = (const char*)(Wb + (long)n0 * 64);
#pragma unroll
    for (int i = 0; i < 4; ++i) {
        int d = i * 4096 + t * 16;
        int srcoff = (d & ~127) | ((d & 127) ^ (((d >> 7) & 7) << 4));
        GLOAD16(Ab + srcoff, (char*)ldsA + d);
        GLOAD16(Bb + srcoff, (char*)ldsB + d);
    }
    __syncthreads();

    f32x4 acc[4][4];
#pragma unroll
    for (int mf = 0; mf < 4; ++mf)
#pragma unroll
        for (int nf = 0; nf < 4; ++nf) acc[mf][nf] = (f32x4){0.f, 0.f, 0.f, 0.f};

#pragma unroll
    for (int kk = 0; kk < 2; ++kk) {
        s16x8 af[4], bfg[4];
#pragma unroll
        for (int f = 0; f < 4; ++f) {
            int ar = wr * 64 + f * 16 + lr;
            af[f] = *(const s16x8*)((const char*)ldsA + ar * 128 +
                                    ((kk * 64 + lkb) ^ ((ar & 7) << 4)));
            int br = wc * 64 + f * 16 + lr;
            bfg[f] = *(const s16x8*)((const char*)ldsB + br * 128 +
                                     ((kk * 64 + lkb) ^ ((br & 7) << 4)));
        }
#pragma unroll
        for (int mf = 0; mf < 4; ++mf)
#pragma unroll
            for (int nf = 0; nf < 4; ++nf)
                acc[mf][nf] = __builtin_amdgcn_mfma_f32_16x16x32_bf16(
                    af[mf], bfg[nf], acc[mf][nf], 0, 0, 0);
    }
    __syncthreads();

#pragma unroll
    for (int nh = 0; nh < 2; ++nh) {
        if (nh) __syncthreads();
        if (wc == nh) {
#pragma unroll
            for (int mf = 0; mf < 4; ++mf)
#pragma unroll
                for (int nf = 0; nf < 4; ++nf)
#pragma unroll
                    for (int r = 0; r < 4; ++r) {
                        int row = wr * 64 + mf * 16 + (l >> 4) * 4 + r;
                        int col = nf * 16 + lr;
                        ldsC[row * 68 + (col ^ (((row >> 3) & 7) << 2))] =
                            acc[mf][nf][r];
                    }
        }
        __syncthreads();
#pragma unroll
        for (int q = 0; q < 2; ++q) {
            int idx = q * 256 + t;
            int ml = idx & 127;
            int oo = idx >> 7;
            int o  = nt * 8 + nh * 4 + oo;
            float bias = ub[o];
            int mg = m0 + ml;
            int b = mg >> 12, pix = mg & 4095;
            int h = pix >> 6, ww = pix & 63;
            long base = ((long)(b * 64 + o) * 256 + h * 4) * 256 + ww * 4;
#pragma unroll
            for (int i = 0; i < 4; ++i) {
                f32x4 cv = *(const f32x4*)&ldsC[ml * 68 +
                            ((oo * 16 + i * 4) ^ (((ml >> 3) & 7) << 2))];
                float4 xi = *(const float4*)&x[base + i * 256];
                float4 rr;
                rr.x = fmaxf(cv[0] + bias + xi.x, 0.f);
                rr.y = fmaxf(cv[1] + bias + xi.y, 0.f);
                rr.z = fmaxf(cv[2] + bias + xi.z, 0.f);
                rr.w = fmaxf(cv[3] + bias + xi.w, 0.f);
                *(float4*)&out[base + i * 256] = rr;
            }
        }
    }
}

// ---------------------------------------------------------------------------
extern "C" void kernel_launch(void* const* d_in, const int* in_sizes, int n_in,
                              void* d_out, int out_size, void* d_ws, size_t ws_size,
                              hipStream_t stream) {
    const float* x      = (const float*)d_in[0];
    const float* weight = (const float*)d_in[1];
    const float* pih_w  = (const float*)d_in[2];
    const float* pih_b  = (const float*)d_in[3];
    const float* up_w   = (const float*)d_in[4];
    const float* up_b   = (const float*)d_in[5];
    float* out = (float*)d_out;
    float* ws  = (float*)d_ws;

    // workspace layout (float offsets)
    u16*   xpc   = (u16*)ws;                   // 2,097,152 u16 NHWC bf16 pooled
    u16*   xpihb = (u16*)(ws + 2097152);       // 2,097,152 u16 conv out bf16 [c][n]
    u16*   Ab16  = (u16*)(ws + 3145728);       // 2,097,152 u16 GEMM A bf16
    float* G     = ws + 4194304;               // 32,768 f
    u16*   Lb16  = (u16*)(ws + 4227072);       // 32,768 u16 L bf16 [b][c][d]
    u16*   Wb    = (u16*)(ws + 4259840);       // 65,536 u16 convT B^T bf16
    u16*   WTb   = (u16*)(ws + 4325376);       // 16,777,216 u16 WT bf16 [N][K]
    u16*   Cp    = (u16*)(ws + 12713984);      // 8,388,608 u16: 4 bf16 partials
    u16*   Bpack = Cp + 2097152;               // conv weights (Cp dead until gemm)
    u16*   A2    = (u16*)ws;                   // out2T bf16 (xpc dead after diffuse)

    hipMemsetAsync(G, 0, 32768 * sizeof(float), stream);
    prep_k        <<<400, 256, 0, stream>>>(up_w, pih_w, Wb, Bpack);
    transWb_k     <<<dim3(64, 64), 256, 0, stream>>>(weight, WTb);
    maxpool_nhwc_k<<<512, 256, 0, stream>>>(x, xpc);
    conv_mfma_k   <<<512, 256, 0, stream>>>(xpc, Bpack, pih_b, xpihb);
    gram_mfma_k   <<<dim3(32, 8), 256, 0, stream>>>(xpihb, G);
    build_L_k     <<<8, 64, 0, stream>>>(G, Lb16);
    diffuse_mfma_k<<<dim3(32, 8), 256, 0, stream>>>(Lb16, xpc, Ab16);
    gemm_mfma_k   <<<512, 256, 0, stream>>>(Ab16, WTb, Cp);
    reduce4T_k    <<<dim3(64, 8), 256, 0, stream>>>(Cp, A2);
    convT_mfma_k  <<<dim3(256, 8), 256, 0, stream>>>(A2, Wb, up_b, x, out);
}